// Round 1
// baseline (373.930 us; speedup 1.0000x reference)
//
#include <hip/hip_runtime.h>
#include <hip/hip_bf16.h>
#include <stdint.h>

// TransformerBlock: B=2 T=2048 D=1024 H=16 HD=64 FF=4096, causal, pre-LN.
// All GEMMs + attention in bf16 MFMA (16x16x32), f32 accum, f32 residual path.

typedef __attribute__((ext_vector_type(8))) __bf16 bf16x8;
typedef __attribute__((ext_vector_type(4))) __bf16 bf16x4;
typedef __attribute__((ext_vector_type(4))) float  f32x4;

#define DD    1024
#define HDIM  64
#define NHEAD 16
#define TSEQ  2048
#define NBAT  2
#define NTOK  4096
#define FFD   4096

__device__ __forceinline__ void gll16(const void* g, void* l) {
  __builtin_amdgcn_global_load_lds(
      (const __attribute__((address_space(1))) unsigned int*)g,
      (__attribute__((address_space(3))) unsigned int*)l, 16, 0, 0);
}

__device__ __forceinline__ float gelu_f(float v) {
  float u = 0.7978845608028654f * (v + 0.044715f * v * v * v);
  float t = 1.0f - 2.0f / (1.0f + __expf(2.0f * u));   // tanh(u), saturates correctly
  return 0.5f * v * (1.0f + t);
}

// ---------------- weight f32 -> bf16 convert (one pass) ----------------
__global__ __launch_bounds__(256) void cvt_weights(
    const float* __restrict__ wq, const float* __restrict__ wk,
    const float* __restrict__ wv, const float* __restrict__ wo,
    const float* __restrict__ w1, const float* __restrict__ w2,
    __bf16* __restrict__ dst)
{
  size_t i4 = (size_t)blockIdx.x * 256 + threadIdx.x;  // float4 index
  size_t e = i4 * 4;
  const float* src; size_t off;
  if (e < (size_t)4 * 1048576) {
    int sel = (int)(e >> 20);
    src = sel == 0 ? wq : sel == 1 ? wk : sel == 2 ? wv : wo;
    off = e & 1048575;
  } else if (e < (size_t)8 * 1048576) {
    src = w1; off = e - (size_t)4 * 1048576;
  } else {
    src = w2; off = e - (size_t)8 * 1048576;
  }
  float4 v = *(const float4*)(src + off);
  bf16x4 o;
  o[0] = (__bf16)v.x; o[1] = (__bf16)v.y; o[2] = (__bf16)v.z; o[3] = (__bf16)v.w;
  *(bf16x4*)(dst + e) = o;
}

// ---------------- LayerNorm: one wave per row, f32 in -> bf16 out ----------------
__global__ __launch_bounds__(256) void ln_kernel(
    const float* __restrict__ x, const float* __restrict__ gw,
    const float* __restrict__ sw, __bf16* __restrict__ out)
{
  const int row  = blockIdx.x * 4 + (threadIdx.x >> 6);
  const int lane = threadIdx.x & 63;
  const float4* xr = (const float4*)(x + (size_t)row * DD);
  float4 v[4];
  float s = 0.f, sq = 0.f;
#pragma unroll
  for (int i = 0; i < 4; ++i) {
    v[i] = xr[i * 64 + lane];
    s  += v[i].x + v[i].y + v[i].z + v[i].w;
    sq += v[i].x * v[i].x + v[i].y * v[i].y + v[i].z * v[i].z + v[i].w * v[i].w;
  }
#pragma unroll
  for (int off = 32; off >= 1; off >>= 1) {
    s  += __shfl_xor(s, off);
    sq += __shfl_xor(sq, off);
  }
  const float mean = s * (1.f / DD);
  const float rstd = rsqrtf(sq * (1.f / DD) - mean * mean + 1e-5f);
  const float4* gr = (const float4*)gw;
  const float4* sr = (const float4*)sw;
#pragma unroll
  for (int i = 0; i < 4; ++i) {
    float4 gv = gr[i * 64 + lane];
    float4 sv = sr[i * 64 + lane];
    bf16x4 o;
    o[0] = (__bf16)(gv.x * (v[i].x - mean) * rstd + sv.x);
    o[1] = (__bf16)(gv.y * (v[i].y - mean) * rstd + sv.y);
    o[2] = (__bf16)(gv.z * (v[i].z - mean) * rstd + sv.z);
    o[3] = (__bf16)(gv.w * (v[i].w - mean) * rstd + sv.w);
    *(bf16x4*)&out[(size_t)row * DD + (size_t)(i * 64 + lane) * 4] = o;
  }
}

// ---------------- GEMM: C[M,N] = A[M,K] @ Bw[N,K]^T  (both K-contiguous) ----------------
// m97 structure: 128x128 tile, BK=64, 4 waves (2x2), 4x4 16x16 frags per wave,
// global_load_lds width-16 staging into linear LDS.
template<bool BIAS, bool GELU, bool RES, bool OUTBF>
__global__ __launch_bounds__(256, 2)
void gemm_bt(const __bf16* __restrict__ A, const __bf16* __restrict__ Bw,
             void* __restrict__ Cout, const float* __restrict__ bias,
             const float* __restrict__ res, int M, int N, int K)
{
  __shared__ __bf16 As[128 * 64];
  __shared__ __bf16 Bs[128 * 64];
  const int t    = threadIdx.x;
  const int lane = t & 63;
  const int l15  = lane & 15;
  const int g    = lane >> 4;
  const int w    = t >> 6;
  const int wr   = w >> 1, wc = w & 1;
  const int m0 = blockIdx.y * 128;
  const int n0 = blockIdx.x * 128;

  const int srow = t >> 3;         // staging row within 32-row chunk
  const int scol = (t & 7) * 8;    // staging col (elements)

  f32x4 acc[4][4] = {};

  const __bf16* Ap = A  + (size_t)m0 * K;
  const __bf16* Bp = Bw + (size_t)n0 * K;

  for (int k0 = 0; k0 < K; k0 += 64) {
#pragma unroll
    for (int i = 0; i < 4; ++i) {
      const int row = i * 32 + srow;
      gll16(Ap + (size_t)row * K + k0 + scol, &As[row * 64 + scol]);
    }
#pragma unroll
    for (int i = 0; i < 4; ++i) {
      const int row = i * 32 + srow;
      gll16(Bp + (size_t)row * K + k0 + scol, &Bs[row * 64 + scol]);
    }
    __syncthreads();
#pragma unroll
    for (int ks = 0; ks < 2; ++ks) {
      bf16x8 af[4], bfr[4];
#pragma unroll
      for (int mi = 0; mi < 4; ++mi)
        af[mi] = *(const bf16x8*)&As[(wr * 64 + mi * 16 + l15) * 64 + ks * 32 + g * 8];
#pragma unroll
      for (int ni = 0; ni < 4; ++ni)
        bfr[ni] = *(const bf16x8*)&Bs[(wc * 64 + ni * 16 + l15) * 64 + ks * 32 + g * 8];
#pragma unroll
      for (int mi = 0; mi < 4; ++mi)
#pragma unroll
        for (int ni = 0; ni < 4; ++ni)
          acc[mi][ni] = __builtin_amdgcn_mfma_f32_16x16x32_bf16(af[mi], bfr[ni], acc[mi][ni], 0, 0, 0);
    }
    __syncthreads();
  }

  // epilogue: C/D layout col = lane&15, row = 4*(lane>>4)+r
  const int crow0 = m0 + wr * 64;
  const int ccol0 = n0 + wc * 64;
#pragma unroll
  for (int mi = 0; mi < 4; ++mi) {
#pragma unroll
    for (int r = 0; r < 4; ++r) {
      const int rr = crow0 + mi * 16 + 4 * g + r;
#pragma unroll
      for (int ni = 0; ni < 4; ++ni) {
        const int cc = ccol0 + ni * 16 + l15;
        float v = acc[mi][ni][r];
        if (BIAS) v += bias[cc];
        if (GELU) v = gelu_f(v);
        if (RES)  v += res[(size_t)rr * N + cc];
        if (OUTBF) ((__bf16*)Cout)[(size_t)rr * N + cc] = (__bf16)v;
        else       ((float*)Cout)[(size_t)rr * N + cc] = v;
      }
    }
  }
}

// ---------------- causal flash attention ----------------
// grid: (qtile=32, head=16, batch=2); 4 waves, each owns 16 q-rows.
// S^T = K @ Q^T via MFMA so softmax reduce over k is lane-local + 2 shfl_xor.
__global__ __launch_bounds__(256, 2)
void attn_kernel(const __bf16* __restrict__ qb, const __bf16* __restrict__ kb,
                 const __bf16* __restrict__ vb, __bf16* __restrict__ ctx)
{
  __shared__ __bf16 Ks[64][72];       // [k][d] +8 pad
  __shared__ __bf16 Vts[64][72];      // [d][k] +8 pad (V transposed)
  __shared__ __bf16 Ps[4][16][72];    // per-wave P [q][k] +8 pad
  const int t    = threadIdx.x;
  const int lane = t & 63;
  const int l15  = lane & 15;
  const int g    = lane >> 4;
  const int w    = t >> 6;
  const int qt = blockIdx.x;
  const int hh = blockIdx.y;
  const int bb = blockIdx.z;
  const int q0 = qt * 64;
  const size_t base = (size_t)bb * TSEQ * DD + (size_t)hh * HDIM;

  // Q fragments in registers (B-operand of S^T mfma): lane holds Q[q=l15][d=8g..]
  const int qrow = q0 + w * 16 + l15;
  bf16x8 qf[2];
  qf[0] = *(const bf16x8*)&qb[base + (size_t)qrow * DD + g * 8];
  qf[1] = *(const bf16x8*)&qb[base + (size_t)qrow * DD + 32 + g * 8];

  f32x4 acc[4] = {};
  float mrun = -1e30f, lrun = 0.f;

  for (int kt = 0; kt <= qt; ++kt) {
    __syncthreads();   // previous tile's compute done before restaging
    {
      const int kk = t >> 2;
      const int d0 = (t & 3) * 16;
      const __bf16* krow = &kb[base + (size_t)(kt * 64 + kk) * DD];
      *(bf16x8*)&Ks[kk][d0]     = *(const bf16x8*)&krow[d0];
      *(bf16x8*)&Ks[kk][d0 + 8] = *(const bf16x8*)&krow[d0 + 8];
      const __bf16* vrow = &vb[base + (size_t)(kt * 64 + kk) * DD];
      bf16x8 v0 = *(const bf16x8*)&vrow[d0];
      bf16x8 v1 = *(const bf16x8*)&vrow[d0 + 8];
#pragma unroll
      for (int j = 0; j < 8; ++j) Vts[d0 + j][kk] = v0[j];
#pragma unroll
      for (int j = 0; j < 8; ++j) Vts[d0 + 8 + j][kk] = v1[j];
    }
    __syncthreads();

    // S^T tile: rows k (4 frags of 16), cols q (16)
    f32x4 s[4];
#pragma unroll
    for (int f = 0; f < 4; ++f) {
      f32x4 z = {};
      bf16x8 a0 = *(const bf16x8*)&Ks[f * 16 + l15][g * 8];
      bf16x8 a1 = *(const bf16x8*)&Ks[f * 16 + l15][32 + g * 8];
      z = __builtin_amdgcn_mfma_f32_16x16x32_bf16(a0, qf[0], z, 0, 0, 0);
      z = __builtin_amdgcn_mfma_f32_16x16x32_bf16(a1, qf[1], z, 0, 0, 0);
      s[f] = z;
    }

    const int qg = q0 + w * 16 + l15;
    float pmax = -1e30f;
#pragma unroll
    for (int f = 0; f < 4; ++f)
#pragma unroll
      for (int r = 0; r < 4; ++r) {
        float sv = s[f][r] * 0.125f;               // 1/sqrt(64)
        const int kg = kt * 64 + f * 16 + g * 4 + r;
        if (kg > qg) sv = -1e30f;                  // causal mask
        s[f][r] = sv;
        pmax = fmaxf(pmax, sv);
      }
    pmax = fmaxf(pmax, __shfl_xor(pmax, 16));
    pmax = fmaxf(pmax, __shfl_xor(pmax, 32));
    const float mnew  = fmaxf(mrun, pmax);
    const float alpha = __expf(mrun - mnew);
    float lsum = 0.f;
#pragma unroll
    for (int f = 0; f < 4; ++f)
#pragma unroll
      for (int r = 0; r < 4; ++r) {
        float p = __expf(s[f][r] - mnew);
        s[f][r] = p;
        lsum += p;
      }
    lsum += __shfl_xor(lsum, 16);
    lsum += __shfl_xor(lsum, 32);
    lrun = lrun * alpha + lsum;
    mrun = mnew;

    // P -> LDS (bf16), [q=l15][k = f*16 + 4g + {0..3}]
#pragma unroll
    for (int f = 0; f < 4; ++f) {
      bf16x4 pk;
      pk[0] = (__bf16)s[f][0]; pk[1] = (__bf16)s[f][1];
      pk[2] = (__bf16)s[f][2]; pk[3] = (__bf16)s[f][3];
      *(bf16x4*)&Ps[w][l15][f * 16 + g * 4] = pk;
    }
    asm volatile("s_waitcnt lgkmcnt(0)" ::: "memory");

    // rescale ctx by alpha[q=4g+r]
    float al[4];
#pragma unroll
    for (int r = 0; r < 4; ++r) al[r] = __shfl(alpha, g * 4 + r);
#pragma unroll
    for (int nf = 0; nf < 4; ++nf)
#pragma unroll
      for (int r = 0; r < 4; ++r) acc[nf][r] *= al[r];

    // ctx += P @ V
#pragma unroll
    for (int ks = 0; ks < 2; ++ks) {
      bf16x8 pa = *(const bf16x8*)&Ps[w][l15][ks * 32 + g * 8];
#pragma unroll
      for (int nf = 0; nf < 4; ++nf) {
        bf16x8 vf = *(const bf16x8*)&Vts[nf * 16 + l15][ks * 32 + g * 8];
        acc[nf] = __builtin_amdgcn_mfma_f32_16x16x32_bf16(pa, vf, acc[nf], 0, 0, 0);
      }
    }
  }

  float li[4];
#pragma unroll
  for (int r = 0; r < 4; ++r) li[r] = 1.0f / __shfl(lrun, g * 4 + r);
#pragma unroll
  for (int nf = 0; nf < 4; ++nf)
#pragma unroll
    for (int r = 0; r < 4; ++r) {
      const int row = q0 + w * 16 + 4 * g + r;
      ctx[base + (size_t)row * DD + nf * 16 + l15] = (__bf16)(acc[nf][r] * li[r]);
    }
}

// ---------------- launcher ----------------
extern "C" void kernel_launch(void* const* d_in, const int* in_sizes, int n_in,
                              void* d_out, int out_size, void* d_ws, size_t ws_size,
                              hipStream_t stream)
{
  (void)in_sizes; (void)n_in; (void)out_size; (void)ws_size;
  const float* x  = (const float*)d_in[0];
  const float* wq = (const float*)d_in[1];
  const float* wk = (const float*)d_in[2];
  const float* wv = (const float*)d_in[3];
  const float* wo = (const float*)d_in[4];
  const float* bo = (const float*)d_in[5];
  const float* w1 = (const float*)d_in[6];
  const float* b1 = (const float*)d_in[7];
  const float* w2 = (const float*)d_in[8];
  const float* b2 = (const float*)d_in[9];
  const float* g1 = (const float*)d_in[10];
  const float* s1 = (const float*)d_in[11];
  const float* g2 = (const float*)d_in[12];
  const float* s2 = (const float*)d_in[13];
  float* out = (float*)d_out;

  char* ws = (char*)d_ws;
  __bf16* wbf  = (__bf16*)ws;                       // 12,582,912 bf16 weights
  size_t o = 25165824;
  __bf16* hbuf = (__bf16*)(ws + o); o += 8388608;   // LN out (reused for LN2)
  __bf16* qb   = (__bf16*)(ws + o); o += 8388608;
  __bf16* kb   = (__bf16*)(ws + o); o += 8388608;
  __bf16* vb   = (__bf16*)(ws + o); o += 8388608;
  __bf16* ctxb = (__bf16*)(ws + o); o += 8388608;
  float*  x2   = (float*)(ws + o);  o += 16777216;
  __bf16* ffb  = (__bf16*)(ws + o); o += 33554432;

  cvt_weights<<<12288, 256, 0, stream>>>(wq, wk, wv, wo, w1, w2, wbf);
  ln_kernel<<<1024, 256, 0, stream>>>(x, g1, s1, hbuf);

  dim3 gq(8, 32);   // N/128, M/128
  gemm_bt<false,false,false,true><<<gq, 256, 0, stream>>>(hbuf, wbf,           qb, nullptr, nullptr, NTOK, DD, DD);
  gemm_bt<false,false,false,true><<<gq, 256, 0, stream>>>(hbuf, wbf + 1048576, kb, nullptr, nullptr, NTOK, DD, DD);
  gemm_bt<false,false,false,true><<<gq, 256, 0, stream>>>(hbuf, wbf + 2097152, vb, nullptr, nullptr, NTOK, DD, DD);

  dim3 ga(32, 16, 2);
  attn_kernel<<<ga, 256, 0, stream>>>(qb, kb, vb, ctxb);

  gemm_bt<true,false,true,false><<<gq, 256, 0, stream>>>(ctxb, wbf + 3145728, x2, bo, x, NTOK, DD, DD);
  ln_kernel<<<1024, 256, 0, stream>>>(x2, g2, s2, hbuf);

  dim3 gf(32, 32);
  gemm_bt<true,true,false,true><<<gf, 256, 0, stream>>>(hbuf, wbf + 4194304, ffb, b1, nullptr, NTOK, FFD, DD);
  gemm_bt<true,false,true,false><<<gq, 256, 0, stream>>>(ffb, wbf + 8388608, out, b2, x2, NTOK, DD, FFD);
}

// Round 2
// 313.196 us; speedup vs baseline: 1.1939x; 1.1939x over previous
//
#include <hip/hip_runtime.h>
#include <hip/hip_bf16.h>
#include <stdint.h>

// TransformerBlock: B=2 T=2048 D=1024 H=16 HD=64 FF=4096, causal, pre-LN.
// All GEMMs + attention in bf16 MFMA (16x16x32), f32 accum, f32 residual path.

typedef __attribute__((ext_vector_type(8))) __bf16 bf16x8;
typedef __attribute__((ext_vector_type(4))) __bf16 bf16x4;
typedef __attribute__((ext_vector_type(4))) float  f32x4;

#define DD    1024
#define HDIM  64
#define NHEAD 16
#define TSEQ  2048
#define NBAT  2
#define NTOK  4096
#define FFD   4096

__device__ __forceinline__ void gll16(const void* g, void* l) {
  __builtin_amdgcn_global_load_lds(
      (const __attribute__((address_space(1))) unsigned int*)g,
      (__attribute__((address_space(3))) unsigned int*)l, 16, 0, 0);
}

__device__ __forceinline__ float gelu_f(float v) {
  float u = 0.7978845608028654f * (v + 0.044715f * v * v * v);
  float t = 1.0f - 2.0f / (1.0f + __expf(2.0f * u));   // tanh(u), saturates correctly
  return 0.5f * v * (1.0f + t);
}

// ---------------- weight f32 -> bf16 convert (one pass) ----------------
__global__ __launch_bounds__(256) void cvt_weights(
    const float* __restrict__ wq, const float* __restrict__ wk,
    const float* __restrict__ wv, const float* __restrict__ wo,
    const float* __restrict__ w1, const float* __restrict__ w2,
    __bf16* __restrict__ dst)
{
  size_t i4 = (size_t)blockIdx.x * 256 + threadIdx.x;  // float4 index
  size_t e = i4 * 4;
  const float* src; size_t off;
  if (e < (size_t)4 * 1048576) {
    int sel = (int)(e >> 20);
    src = sel == 0 ? wq : sel == 1 ? wk : sel == 2 ? wv : wo;
    off = e & 1048575;
  } else if (e < (size_t)8 * 1048576) {
    src = w1; off = e - (size_t)4 * 1048576;
  } else {
    src = w2; off = e - (size_t)8 * 1048576;
  }
  float4 v = *(const float4*)(src + off);
  bf16x4 o;
  o[0] = (__bf16)v.x; o[1] = (__bf16)v.y; o[2] = (__bf16)v.z; o[3] = (__bf16)v.w;
  *(bf16x4*)(dst + e) = o;
}

// ---------------- LayerNorm: one wave per row, f32 in -> bf16 out ----------------
__global__ __launch_bounds__(256) void ln_kernel(
    const float* __restrict__ x, const float* __restrict__ gw,
    const float* __restrict__ sw, __bf16* __restrict__ out)
{
  const int row  = blockIdx.x * 4 + (threadIdx.x >> 6);
  const int lane = threadIdx.x & 63;
  const float4* xr = (const float4*)(x + (size_t)row * DD);
  float4 v[4];
  float s = 0.f, sq = 0.f;
#pragma unroll
  for (int i = 0; i < 4; ++i) {
    v[i] = xr[i * 64 + lane];
    s  += v[i].x + v[i].y + v[i].z + v[i].w;
    sq += v[i].x * v[i].x + v[i].y * v[i].y + v[i].z * v[i].z + v[i].w * v[i].w;
  }
#pragma unroll
  for (int off = 32; off >= 1; off >>= 1) {
    s  += __shfl_xor(s, off);
    sq += __shfl_xor(sq, off);
  }
  const float mean = s * (1.f / DD);
  const float rstd = rsqrtf(sq * (1.f / DD) - mean * mean + 1e-5f);
  const float4* gr = (const float4*)gw;
  const float4* sr = (const float4*)sw;
#pragma unroll
  for (int i = 0; i < 4; ++i) {
    float4 gv = gr[i * 64 + lane];
    float4 sv = sr[i * 64 + lane];
    bf16x4 o;
    o[0] = (__bf16)(gv.x * (v[i].x - mean) * rstd + sv.x);
    o[1] = (__bf16)(gv.y * (v[i].y - mean) * rstd + sv.y);
    o[2] = (__bf16)(gv.z * (v[i].z - mean) * rstd + sv.z);
    o[3] = (__bf16)(gv.w * (v[i].w - mean) * rstd + sv.w);
    *(bf16x4*)&out[(size_t)row * DD + (size_t)(i * 64 + lane) * 4] = o;
  }
}

// ---------------- GEMM: C[M,N] = A[M,K] @ Bw[N,K]^T  (both K-contiguous) ----------------
// m97 structure: 128x128 tile, BK=64, 4 waves (2x2), 4x4 16x16 frags per wave,
// global_load_lds width-16 staging into linear LDS.
// QKV mode: N=3072 fused; cols >=2048 (V) are written TRANSPOSED to voutT[b][h][d][t];
// cols <2048 (Q,K) go to Cout with row stride 2048.
template<bool BIAS, bool GELU, bool RES, bool OUTBF, bool QKV>
__global__ __launch_bounds__(256, 3)
void gemm_bt(const __bf16* __restrict__ A, const __bf16* __restrict__ Bw,
             void* __restrict__ Cout, const float* __restrict__ bias,
             const float* __restrict__ res, __bf16* __restrict__ voutT,
             int M, int N, int K)
{
  __shared__ __bf16 As[128 * 64];
  __shared__ __bf16 Bs[128 * 64];
  const int t    = threadIdx.x;
  const int lane = t & 63;
  const int l15  = lane & 15;
  const int g    = lane >> 4;
  const int w    = t >> 6;
  const int wr   = w >> 1, wc = w & 1;
  const int m0 = blockIdx.y * 128;
  const int n0 = blockIdx.x * 128;

  const int srow = t >> 3;         // staging row within 32-row chunk
  const int scol = (t & 7) * 8;    // staging col (elements)

  f32x4 acc[4][4] = {};

  const __bf16* Ap = A  + (size_t)m0 * K;
  const __bf16* Bp = Bw + (size_t)n0 * K;

  for (int k0 = 0; k0 < K; k0 += 64) {
#pragma unroll
    for (int i = 0; i < 4; ++i) {
      const int row = i * 32 + srow;
      gll16(Ap + (size_t)row * K + k0 + scol, &As[row * 64 + scol]);
    }
#pragma unroll
    for (int i = 0; i < 4; ++i) {
      const int row = i * 32 + srow;
      gll16(Bp + (size_t)row * K + k0 + scol, &Bs[row * 64 + scol]);
    }
    __syncthreads();
#pragma unroll
    for (int ks = 0; ks < 2; ++ks) {
      bf16x8 af[4], bfr[4];
#pragma unroll
      for (int mi = 0; mi < 4; ++mi)
        af[mi] = *(const bf16x8*)&As[(wr * 64 + mi * 16 + l15) * 64 + ks * 32 + g * 8];
#pragma unroll
      for (int ni = 0; ni < 4; ++ni)
        bfr[ni] = *(const bf16x8*)&Bs[(wc * 64 + ni * 16 + l15) * 64 + ks * 32 + g * 8];
#pragma unroll
      for (int mi = 0; mi < 4; ++mi)
#pragma unroll
        for (int ni = 0; ni < 4; ++ni)
          acc[mi][ni] = __builtin_amdgcn_mfma_f32_16x16x32_bf16(af[mi], bfr[ni], acc[mi][ni], 0, 0, 0);
    }
    __syncthreads();
  }

  // epilogue: C/D layout col = lane&15, row = 4*(lane>>4)+r
  const int crow0 = m0 + wr * 64;
  const int ccol0 = n0 + wc * 64;

  if (QKV && n0 >= 2048) {
    // V columns: write transposed to voutT[b][h][d][t]  ([2][16][64][2048])
#pragma unroll
    for (int mi = 0; mi < 4; ++mi) {
      const int rr0 = crow0 + mi * 16 + 4 * g;   // token row base (4 consecutive)
      const int b  = rr0 >> 11;
      const int t0 = rr0 & 2047;
#pragma unroll
      for (int ni = 0; ni < 4; ++ni) {
        const int cc = ccol0 + ni * 16 + l15 - 2048;   // 0..1023
        const int h = cc >> 6, d = cc & 63;
        bf16x4 o;
        o[0] = (__bf16)acc[mi][ni][0];
        o[1] = (__bf16)acc[mi][ni][1];
        o[2] = (__bf16)acc[mi][ni][2];
        o[3] = (__bf16)acc[mi][ni][3];
        *(bf16x4*)&voutT[(((size_t)(b * 16 + h)) * 64 + d) * 2048 + t0] = o;
      }
    }
    return;
  }

  const int ldc = QKV ? 2048 : N;
#pragma unroll
  for (int mi = 0; mi < 4; ++mi) {
#pragma unroll
    for (int r = 0; r < 4; ++r) {
      const int rr = crow0 + mi * 16 + 4 * g + r;
#pragma unroll
      for (int ni = 0; ni < 4; ++ni) {
        const int cc = ccol0 + ni * 16 + l15;
        float v = acc[mi][ni][r];
        if (BIAS) v += bias[cc];
        if (GELU) v = gelu_f(v);
        if (RES)  v += res[(size_t)rr * N + cc];
        if (OUTBF) ((__bf16*)Cout)[(size_t)rr * ldc + cc] = (__bf16)v;
        else       ((float*)Cout)[(size_t)rr * ldc + cc] = v;
      }
    }
  }
}

// ---------------- causal flash attention ----------------
// grid: (qtile=32 REVERSED, head=16, batch=2); 4 waves, each owns 16 q-rows.
// S^T = K @ Q^T via MFMA so softmax reduce over k is lane-local + 2 shfl_xor.
// Q,K read from fused qk buffer [4096][2048]; V read pre-transposed vT[b][h][d][t].
__global__ __launch_bounds__(256, 2)
void attn_kernel(const __bf16* __restrict__ qk, const __bf16* __restrict__ vT,
                 __bf16* __restrict__ ctx)
{
  __shared__ __bf16 Ks[64][72];       // [k][d] +8 pad
  __shared__ __bf16 VTs[64][72];      // [d][k] +8 pad (direct row copy from vT)
  __shared__ __bf16 Ps[4][16][72];    // per-wave P [q][k] +8 pad
  const int t    = threadIdx.x;
  const int lane = t & 63;
  const int l15  = lane & 15;
  const int g    = lane >> 4;
  const int w    = t >> 6;
  const int qt = gridDim.x - 1 - blockIdx.x;   // heavy blocks dispatch first
  const int hh = blockIdx.y;
  const int bb = blockIdx.z;
  const int q0 = qt * 64;

  // Q fragments in registers (B-operand of S^T mfma): lane holds Q[q=l15][d=8g..]
  const int qrow = q0 + w * 16 + l15;
  const size_t qkrow = ((size_t)(bb * 2048 + qrow)) * 2048 + hh * 64;
  bf16x8 qf[2];
  qf[0] = *(const bf16x8*)&qk[qkrow + g * 8];
  qf[1] = *(const bf16x8*)&qk[qkrow + 32 + g * 8];

  f32x4 acc[4] = {};
  float mrun = -1e30f, lrun = 0.f;

  for (int kt = 0; kt <= qt; ++kt) {
    __syncthreads();   // previous tile's compute done before restaging
    {
      // K tile: row-major copy (conflict-free pattern)
      const int kk = t >> 2;
      const int d0 = (t & 3) * 16;
      const __bf16* krow = &qk[((size_t)(bb * 2048 + kt * 64 + kk)) * 2048 + 1024 + hh * 64];
      *(bf16x8*)&Ks[kk][d0]     = *(const bf16x8*)&krow[d0];
      *(bf16x8*)&Ks[kk][d0 + 8] = *(const bf16x8*)&krow[d0 + 8];
      // V^T tile: direct row-major copy from pre-transposed vT (same pattern)
      const int dd = t >> 2;
      const int c0 = (t & 3) * 16;
      const __bf16* vrow = &vT[(((size_t)(bb * 16 + hh)) * 64 + dd) * 2048 + kt * 64 + c0];
      *(bf16x8*)&VTs[dd][c0]     = *(const bf16x8*)&vrow[0];
      *(bf16x8*)&VTs[dd][c0 + 8] = *(const bf16x8*)&vrow[8];
    }
    __syncthreads();

    // S^T tile: rows k (4 frags of 16), cols q (16)
    f32x4 s[4];
#pragma unroll
    for (int f = 0; f < 4; ++f) {
      f32x4 z = {};
      bf16x8 a0 = *(const bf16x8*)&Ks[f * 16 + l15][g * 8];
      bf16x8 a1 = *(const bf16x8*)&Ks[f * 16 + l15][32 + g * 8];
      z = __builtin_amdgcn_mfma_f32_16x16x32_bf16(a0, qf[0], z, 0, 0, 0);
      z = __builtin_amdgcn_mfma_f32_16x16x32_bf16(a1, qf[1], z, 0, 0, 0);
      s[f] = z;
    }

    const int qg = q0 + w * 16 + l15;
    float pmax = -1e30f;
#pragma unroll
    for (int f = 0; f < 4; ++f)
#pragma unroll
      for (int r = 0; r < 4; ++r) {
        float sv = s[f][r] * 0.125f;               // 1/sqrt(64)
        const int kg = kt * 64 + f * 16 + g * 4 + r;
        if (kg > qg) sv = -1e30f;                  // causal mask
        s[f][r] = sv;
        pmax = fmaxf(pmax, sv);
      }
    pmax = fmaxf(pmax, __shfl_xor(pmax, 16));
    pmax = fmaxf(pmax, __shfl_xor(pmax, 32));
    const float mnew  = fmaxf(mrun, pmax);
    const float alpha = __expf(mrun - mnew);
    float lsum = 0.f;
#pragma unroll
    for (int f = 0; f < 4; ++f)
#pragma unroll
      for (int r = 0; r < 4; ++r) {
        float p = __expf(s[f][r] - mnew);
        s[f][r] = p;
        lsum += p;
      }
    lsum += __shfl_xor(lsum, 16);
    lsum += __shfl_xor(lsum, 32);
    lrun = lrun * alpha + lsum;
    mrun = mnew;

    // P -> LDS (bf16), [q=l15][k = f*16 + 4g + {0..3}]
#pragma unroll
    for (int f = 0; f < 4; ++f) {
      bf16x4 pk;
      pk[0] = (__bf16)s[f][0]; pk[1] = (__bf16)s[f][1];
      pk[2] = (__bf16)s[f][2]; pk[3] = (__bf16)s[f][3];
      *(bf16x4*)&Ps[w][l15][f * 16 + g * 4] = pk;
    }
    asm volatile("s_waitcnt lgkmcnt(0)" ::: "memory");

    // rescale ctx by alpha[q=4g+r]
    float al[4];
#pragma unroll
    for (int r = 0; r < 4; ++r) al[r] = __shfl(alpha, g * 4 + r);
#pragma unroll
    for (int nf = 0; nf < 4; ++nf)
#pragma unroll
      for (int r = 0; r < 4; ++r) acc[nf][r] *= al[r];

    // ctx += P @ V   (B-frag read straight from VTs rows: V[k][d] = VTs[d][k])
#pragma unroll
    for (int ks = 0; ks < 2; ++ks) {
      bf16x8 pa = *(const bf16x8*)&Ps[w][l15][ks * 32 + g * 8];
#pragma unroll
      for (int nf = 0; nf < 4; ++nf) {
        bf16x8 vf = *(const bf16x8*)&VTs[nf * 16 + l15][ks * 32 + g * 8];
        acc[nf] = __builtin_amdgcn_mfma_f32_16x16x32_bf16(pa, vf, acc[nf], 0, 0, 0);
      }
    }
  }

  float li[4];
#pragma unroll
  for (int r = 0; r < 4; ++r) li[r] = 1.0f / __shfl(lrun, g * 4 + r);
#pragma unroll
  for (int nf = 0; nf < 4; ++nf)
#pragma unroll
    for (int r = 0; r < 4; ++r) {
      const int row = q0 + w * 16 + 4 * g + r;
      ctx[((size_t)(bb * 2048 + row)) * DD + hh * 64 + nf * 16 + l15] =
          (__bf16)(acc[nf][r] * li[r]);
    }
}

// ---------------- launcher ----------------
extern "C" void kernel_launch(void* const* d_in, const int* in_sizes, int n_in,
                              void* d_out, int out_size, void* d_ws, size_t ws_size,
                              hipStream_t stream)
{
  (void)in_sizes; (void)n_in; (void)out_size; (void)ws_size;
  const float* x  = (const float*)d_in[0];
  const float* wq = (const float*)d_in[1];
  const float* wk = (const float*)d_in[2];
  const float* wv = (const float*)d_in[3];
  const float* wo = (const float*)d_in[4];
  const float* bo = (const float*)d_in[5];
  const float* w1 = (const float*)d_in[6];
  const float* b1 = (const float*)d_in[7];
  const float* w2 = (const float*)d_in[8];
  const float* b2 = (const float*)d_in[9];
  const float* g1 = (const float*)d_in[10];
  const float* s1 = (const float*)d_in[11];
  const float* g2 = (const float*)d_in[12];
  const float* s2 = (const float*)d_in[13];
  float* out = (float*)d_out;

  char* ws = (char*)d_ws;
  __bf16* wbf  = (__bf16*)ws;                       // 12,582,912 bf16 weights (q,k,v,o,w1,w2)
  size_t o = 25165824;
  __bf16* hbuf = (__bf16*)(ws + o); o += 8388608;   // LN out (reused for LN2)
  __bf16* qkb  = (__bf16*)(ws + o); o += 16777216;  // fused Q|K  [4096][2048]
  __bf16* vbT  = (__bf16*)(ws + o); o += 8388608;   // V^T [2][16][64][2048]
  __bf16* ctxb = (__bf16*)(ws + o); o += 8388608;
  float*  x2   = (float*)(ws + o);  o += 16777216;
  __bf16* ffb  = (__bf16*)(ws + o); o += 33554432;

  cvt_weights<<<12288, 256, 0, stream>>>(wq, wk, wv, wo, w1, w2, wbf);
  ln_kernel<<<1024, 256, 0, stream>>>(x, g1, s1, hbuf);

  // fused QKV: N=3072 (wq|wk|wv rows contiguous in wbf)
  dim3 gqkv(24, 32);
  gemm_bt<false,false,false,true,true><<<gqkv, 256, 0, stream>>>(
      hbuf, wbf, qkb, nullptr, nullptr, vbT, NTOK, 3072, DD);

  dim3 ga(32, 16, 2);
  attn_kernel<<<ga, 256, 0, stream>>>(qkb, vbT, ctxb);

  dim3 gq(8, 32);
  gemm_bt<true,false,true,false,false><<<gq, 256, 0, stream>>>(
      ctxb, wbf + 3145728, x2, bo, x, nullptr, NTOK, DD, DD);
  ln_kernel<<<1024, 256, 0, stream>>>(x2, g2, s2, hbuf);

  dim3 gf(32, 32);
  gemm_bt<true,true,false,true,false><<<gf, 256, 0, stream>>>(
      hbuf, wbf + 4194304, ffb, b1, nullptr, nullptr, NTOK, FFD, DD);
  gemm_bt<true,false,true,false,false><<<gq, 256, 0, stream>>>(
      ffb, wbf + 8388608, out, b2, x2, nullptr, NTOK, DD, FFD);
}

// Round 5
// 284.602 us; speedup vs baseline: 1.3139x; 1.1005x over previous
//
#include <hip/hip_runtime.h>
#include <hip/hip_bf16.h>
#include <stdint.h>

// TransformerBlock: B=2 T=2048 D=1024 H=16 HD=64 FF=4096, causal, pre-LN.
// GEMMs + attention in bf16 MFMA (16x16x32), f32 accum, f32 residual path.

typedef __attribute__((ext_vector_type(8))) __bf16 bf16x8;
typedef __attribute__((ext_vector_type(4))) __bf16 bf16x4;
typedef __attribute__((ext_vector_type(4))) float  f32x4;

#define DD    1024
#define TSEQ  2048
#define NTOK  4096
#define FFD   4096

#define ASM_VMCNT8() asm volatile("s_waitcnt vmcnt(8)" ::: "memory")
#define ASM_VMCNT0() asm volatile("s_waitcnt vmcnt(0)" ::: "memory")
#define ASM_LGKM0()  asm volatile("s_waitcnt lgkmcnt(0)" ::: "memory")

__device__ __forceinline__ void gll16(const void* g, void* l) {
  __builtin_amdgcn_global_load_lds(
      (const __attribute__((address_space(1))) unsigned int*)g,
      (__attribute__((address_space(3))) unsigned int*)l, 16, 0, 0);
}

__device__ __forceinline__ float gelu_f(float v) {
  float u = 0.7978845608028654f * (v + 0.044715f * v * v * v);
  float t = 1.0f - 2.0f / (1.0f + __expf(2.0f * u));   // tanh(u)
  return 0.5f * v * (1.0f + t);
}

// ---------------- weight f32 -> bf16 convert ----------------
__global__ __launch_bounds__(256) void cvt_weights(
    const float* __restrict__ wq, const float* __restrict__ wk,
    const float* __restrict__ wv, const float* __restrict__ wo,
    const float* __restrict__ w1, const float* __restrict__ w2,
    __bf16* __restrict__ dst)
{
  size_t i4 = (size_t)blockIdx.x * 256 + threadIdx.x;
  size_t e = i4 * 4;
  const float* src; size_t off;
  if (e < (size_t)4 * 1048576) {
    int sel = (int)(e >> 20);
    src = sel == 0 ? wq : sel == 1 ? wk : sel == 2 ? wv : wo;
    off = e & 1048575;
  } else if (e < (size_t)8 * 1048576) {
    src = w1; off = e - (size_t)4 * 1048576;
  } else {
    src = w2; off = e - (size_t)8 * 1048576;
  }
  float4 v = *(const float4*)(src + off);
  bf16x4 o;
  o[0] = (__bf16)v.x; o[1] = (__bf16)v.y; o[2] = (__bf16)v.z; o[3] = (__bf16)v.w;
  *(bf16x4*)(dst + e) = o;
}

// ---------------- LayerNorm: one wave per row ----------------
__global__ __launch_bounds__(256) void ln_kernel(
    const float* __restrict__ x, const float* __restrict__ gw,
    const float* __restrict__ sw, __bf16* __restrict__ out)
{
  const int row  = blockIdx.x * 4 + (threadIdx.x >> 6);
  const int lane = threadIdx.x & 63;
  const float4* xr = (const float4*)(x + (size_t)row * DD);
  float4 v[4];
  float s = 0.f, sq = 0.f;
#pragma unroll
  for (int i = 0; i < 4; ++i) {
    v[i] = xr[i * 64 + lane];
    s  += v[i].x + v[i].y + v[i].z + v[i].w;
    sq += v[i].x * v[i].x + v[i].y * v[i].y + v[i].z * v[i].z + v[i].w * v[i].w;
  }
#pragma unroll
  for (int off = 32; off >= 1; off >>= 1) {
    s  += __shfl_xor(s, off);
    sq += __shfl_xor(sq, off);
  }
  const float mean = s * (1.f / DD);
  const float rstd = rsqrtf(sq * (1.f / DD) - mean * mean + 1e-5f);
  const float4* gr = (const float4*)gw;
  const float4* sr = (const float4*)sw;
#pragma unroll
  for (int i = 0; i < 4; ++i) {
    float4 gv = gr[i * 64 + lane];
    float4 sv = sr[i * 64 + lane];
    bf16x4 o;
    o[0] = (__bf16)(gv.x * (v[i].x - mean) * rstd + sv.x);
    o[1] = (__bf16)(gv.y * (v[i].y - mean) * rstd + sv.y);
    o[2] = (__bf16)(gv.z * (v[i].z - mean) * rstd + sv.z);
    o[3] = (__bf16)(gv.w * (v[i].w - mean) * rstd + sv.w);
    *(bf16x4*)&out[(size_t)row * DD + (size_t)(i * 64 + lane) * 4] = o;
  }
}

// ================= deep-pipelined 256x256 GEMM =================
// C[M,N] = A[M,K(lda)] @ Bw[N,K(ldb)]^T. 512 thr / 8 waves (2x4).
// STATIC 128KB LDS: 2 K-tile buffers, counted vmcnt(8) 2-tile prefetch,
// raw s_barrier, T2 chunk-XOR swizzle (source-swizzled stage, XOR read).
// MODE: 0=QKV (bf16, V transposed to voutT), 1=bias+gelu bf16, 2=bf16 partial.
template<int MODE>
__global__ __launch_bounds__(512, 2)
void gemm256(const __bf16* __restrict__ A, int lda,
             const __bf16* __restrict__ Bw, int ldb,
             __bf16* __restrict__ Cout, const float* __restrict__ bias,
             __bf16* __restrict__ voutT, int M, int N, int K)
{
  __shared__ __bf16 sm[65536];          // [buf][A/B][256*64] = 128 KiB static
  const int t = threadIdx.x;
  const int lane = t & 63;
  const int l15 = lane & 15, g = lane >> 4;
  const int w = t >> 6;
  const int wm = w >> 2, wn = w & 3;    // 2 x 4 wave grid
  const int m0 = blockIdx.y * 256, n0 = blockIdx.x * 256;

  if (MODE == 2) {                      // split-K offsets
    const int kz = blockIdx.z;
    A    += (size_t)kz * 1024;
    Bw   += (size_t)kz * 1024;
    Cout += (size_t)kz * (size_t)M * N;
  }

  const int srow = t >> 3;              // 0..63 within a 64-row round
  const int schunk = t & 7;             // LDS 16B-chunk 0..7

  auto STAGE = [&](int kt, int b) {
    const int k0 = kt * 64;
    __bf16* dA = sm + b * 32768;
    __bf16* dB = sm + b * 32768 + 16384;
#pragma unroll
    for (int ro = 0; ro < 4; ++ro) {
      const int row = ro * 64 + srow;
      const int gc = schunk ^ (row & 7);          // pre-swizzled source chunk
      gll16(A + (size_t)(m0 + row) * lda + k0 + gc * 8, dA + row * 64 + schunk * 8);
    }
#pragma unroll
    for (int ro = 0; ro < 4; ++ro) {
      const int row = ro * 64 + srow;
      const int gc = schunk ^ (row & 7);
      gll16(Bw + (size_t)(n0 + row) * ldb + k0 + gc * 8, dB + row * 64 + schunk * 8);
    }
  };

  f32x4 acc[8][4] = {};
  const int NT = K >> 6;

  STAGE(0, 0);
  STAGE(1, 1);
  ASM_VMCNT8();                          // tile 0 landed (own wave)
  __builtin_amdgcn_s_barrier();          // all waves' tile 0 landed

  for (int kt = 0; kt < NT; ++kt) {
    const int cb = kt & 1;
    const __bf16* sA = sm + cb * 32768;
    const __bf16* sB = sm + cb * 32768 + 16384;

    bf16x8 af[8][2], bfr[4][2];
#pragma unroll
    for (int mi = 0; mi < 8; ++mi) {
      const int row = wm * 128 + mi * 16 + l15;
#pragma unroll
      for (int ks = 0; ks < 2; ++ks) {
        const int ch = (ks * 4 + g) ^ (row & 7);
        af[mi][ks] = *(const bf16x8*)&sA[row * 64 + ch * 8];
      }
    }
#pragma unroll
    for (int ni = 0; ni < 4; ++ni) {
      const int row = wn * 64 + ni * 16 + l15;
#pragma unroll
      for (int ks = 0; ks < 2; ++ks) {
        const int ch = (ks * 4 + g) ^ (row & 7);
        bfr[ni][ks] = *(const bf16x8*)&sB[row * 64 + ch * 8];
      }
    }
    ASM_LGKM0();                         // own reads of buf[cb] complete
    __builtin_amdgcn_s_barrier();        // everyone's reads complete
    if (kt + 2 < NT) STAGE(kt + 2, cb);  // safe: all reads of cb retired

    __builtin_amdgcn_s_setprio(1);
#pragma unroll
    for (int ks = 0; ks < 2; ++ks)
#pragma unroll
      for (int mi = 0; mi < 8; ++mi)
#pragma unroll
        for (int ni = 0; ni < 4; ++ni)
          acc[mi][ni] = __builtin_amdgcn_mfma_f32_16x16x32_bf16(
              af[mi][ks], bfr[ni][ks], acc[mi][ni], 0, 0, 0);
    __builtin_amdgcn_s_setprio(0);

    if (kt + 1 < NT) {
      if (kt + 2 < NT) ASM_VMCNT8();     // tile kt+1 landed, kt+2 in flight
      else             ASM_VMCNT0();     // drain everything before last tile
      __builtin_amdgcn_s_barrier();
    }
  }

  // epilogue: C/D frag layout col = lane&15, row = 4*(lane>>4)+r
#pragma unroll
  for (int mi = 0; mi < 8; ++mi) {
    const int rr0 = m0 + wm * 128 + mi * 16 + 4 * g;
#pragma unroll
    for (int ni = 0; ni < 4; ++ni) {
      const int cc = n0 + wn * 64 + ni * 16 + l15;
      if (MODE == 0 && n0 + wn * 64 >= 2048) {
        // V: write transposed vT[b][h][d][t], 4 consecutive tokens vectorized
        const int b  = rr0 >> 11;
        const int t0 = rr0 & 2047;
        const int vc = cc - 2048;
        const int h = vc >> 6, d = vc & 63;
        bf16x4 o;
        o[0] = (__bf16)acc[mi][ni][0]; o[1] = (__bf16)acc[mi][ni][1];
        o[2] = (__bf16)acc[mi][ni][2]; o[3] = (__bf16)acc[mi][ni][3];
        *(bf16x4*)&voutT[(((size_t)(b * 16 + h)) * 64 + d) * 2048 + t0] = o;
      } else {
        const int ldc = (MODE == 0) ? 2048 : N;
#pragma unroll
        for (int r = 0; r < 4; ++r) {
          float v = acc[mi][ni][r];
          if (MODE == 1) { v += bias[cc]; v = gelu_f(v); }
          Cout[(size_t)(rr0 + r) * ldc + cc] = (__bf16)v;
        }
      }
    }
  }
}

// ---------------- FF2 reduce: out = x2 + b2 + sum(partials) ----------------
// out has 4,194,304 elements; 256 thr x 4 elems -> EXACTLY 4096 blocks.
__global__ __launch_bounds__(256) void ff2_reduce(
    const __bf16* __restrict__ part, const float* __restrict__ x2,
    const float* __restrict__ b2, float* __restrict__ out)
{
  const size_t e = ((size_t)blockIdx.x * 256 + threadIdx.x) * 4;
  float4 r = *(const float4*)(x2 + e);
  const float4 b = *(const float4*)(b2 + (e & 1023));
  r.x += b.x; r.y += b.y; r.z += b.z; r.w += b.w;
#pragma unroll
  for (int s = 0; s < 4; ++s) {
    bf16x4 p = *(const bf16x4*)(part + (size_t)s * 4194304 + e);
    r.x += (float)p[0]; r.y += (float)p[1]; r.z += (float)p[2]; r.w += (float)p[3];
  }
  *(float4*)(out + e) = r;
}

// ---------------- legacy 128x128 GEMM (WO only) ----------------
template<bool BIAS, bool RES>
__global__ __launch_bounds__(256, 3)
void gemm_bt(const __bf16* __restrict__ A, const __bf16* __restrict__ Bw,
             float* __restrict__ Cout, const float* __restrict__ bias,
             const float* __restrict__ res, int M, int N, int K)
{
  __shared__ __bf16 As[128 * 64];
  __shared__ __bf16 Bs[128 * 64];
  const int t    = threadIdx.x;
  const int lane = t & 63;
  const int l15  = lane & 15;
  const int g    = lane >> 4;
  const int w    = t >> 6;
  const int wr   = w >> 1, wc = w & 1;
  const int m0 = blockIdx.y * 128;
  const int n0 = blockIdx.x * 128;
  const int srow = t >> 3;
  const int scol = (t & 7) * 8;

  f32x4 acc[4][4] = {};
  const __bf16* Ap = A  + (size_t)m0 * K;
  const __bf16* Bp = Bw + (size_t)n0 * K;

  for (int k0 = 0; k0 < K; k0 += 64) {
#pragma unroll
    for (int i = 0; i < 4; ++i) {
      const int row = i * 32 + srow;
      gll16(Ap + (size_t)row * K + k0 + scol, &As[row * 64 + scol]);
    }
#pragma unroll
    for (int i = 0; i < 4; ++i) {
      const int row = i * 32 + srow;
      gll16(Bp + (size_t)row * K + k0 + scol, &Bs[row * 64 + scol]);
    }
    __syncthreads();
#pragma unroll
    for (int ks = 0; ks < 2; ++ks) {
      bf16x8 af[4], bfr[4];
#pragma unroll
      for (int mi = 0; mi < 4; ++mi)
        af[mi] = *(const bf16x8*)&As[(wr * 64 + mi * 16 + l15) * 64 + ks * 32 + g * 8];
#pragma unroll
      for (int ni = 0; ni < 4; ++ni)
        bfr[ni] = *(const bf16x8*)&Bs[(wc * 64 + ni * 16 + l15) * 64 + ks * 32 + g * 8];
#pragma unroll
      for (int mi = 0; mi < 4; ++mi)
#pragma unroll
        for (int ni = 0; ni < 4; ++ni)
          acc[mi][ni] = __builtin_amdgcn_mfma_f32_16x16x32_bf16(af[mi], bfr[ni], acc[mi][ni], 0, 0, 0);
    }
    __syncthreads();
  }

  const int crow0 = m0 + wr * 64;
  const int ccol0 = n0 + wc * 64;
#pragma unroll
  for (int mi = 0; mi < 4; ++mi) {
#pragma unroll
    for (int r = 0; r < 4; ++r) {
      const int rr = crow0 + mi * 16 + 4 * g + r;
#pragma unroll
      for (int ni = 0; ni < 4; ++ni) {
        const int cc = ccol0 + ni * 16 + l15;
        float v = acc[mi][ni][r];
        if (BIAS) v += bias[cc];
        if (RES)  v += res[(size_t)rr * N + cc];
        Cout[(size_t)rr * N + cc] = v;
      }
    }
  }
}

// ---------------- causal flash attention ----------------
__global__ __launch_bounds__(256, 2)
void attn_kernel(const __bf16* __restrict__ qk, const __bf16* __restrict__ vT,
                 __bf16* __restrict__ ctx)
{
  __shared__ __bf16 Ks[64][72];
  __shared__ __bf16 VTs[64][72];
  __shared__ __bf16 Ps[4][16][72];
  const int t    = threadIdx.x;
  const int lane = t & 63;
  const int l15  = lane & 15;
  const int g    = lane >> 4;
  const int w    = t >> 6;
  const int qt = gridDim.x - 1 - blockIdx.x;
  const int hh = blockIdx.y;
  const int bb = blockIdx.z;
  const int q0 = qt * 64;

  const int qrow = q0 + w * 16 + l15;
  const size_t qkrow = ((size_t)(bb * 2048 + qrow)) * 2048 + hh * 64;
  bf16x8 qf[2];
  qf[0] = *(const bf16x8*)&qk[qkrow + g * 8];
  qf[1] = *(const bf16x8*)&qk[qkrow + 32 + g * 8];

  f32x4 acc[4] = {};
  float mrun = -1e30f, lrun = 0.f;

  for (int kt = 0; kt <= qt; ++kt) {
    __syncthreads();
    {
      const int kk = t >> 2;
      const int d0 = (t & 3) * 16;
      const __bf16* krow = &qk[((size_t)(bb * 2048 + kt * 64 + kk)) * 2048 + 1024 + hh * 64];
      *(bf16x8*)&Ks[kk][d0]     = *(const bf16x8*)&krow[d0];
      *(bf16x8*)&Ks[kk][d0 + 8] = *(const bf16x8*)&krow[d0 + 8];
      const __bf16* vrow = &vT[(((size_t)(bb * 16 + hh)) * 64 + kk) * 2048 + kt * 64 + d0];
      *(bf16x8*)&VTs[kk][d0]     = *(const bf16x8*)&vrow[0];
      *(bf16x8*)&VTs[kk][d0 + 8] = *(const bf16x8*)&vrow[8];
    }
    __syncthreads();

    f32x4 s[4];
#pragma unroll
    for (int f = 0; f < 4; ++f) {
      f32x4 z = {};
      bf16x8 a0 = *(const bf16x8*)&Ks[f * 16 + l15][g * 8];
      bf16x8 a1 = *(const bf16x8*)&Ks[f * 16 + l15][32 + g * 8];
      z = __builtin_amdgcn_mfma_f32_16x16x32_bf16(a0, qf[0], z, 0, 0, 0);
      z = __builtin_amdgcn_mfma_f32_16x16x32_bf16(a1, qf[1], z, 0, 0, 0);
      s[f] = z;
    }

    const int qg = q0 + w * 16 + l15;
    float pmax = -1e30f;
#pragma unroll
    for (int f = 0; f < 4; ++f)
#pragma unroll
      for (int r = 0; r < 4; ++r) {
        float sv = s[f][r] * 0.125f;
        const int kg = kt * 64 + f * 16 + g * 4 + r;
        if (kg > qg) sv = -1e30f;
        s[f][r] = sv;
        pmax = fmaxf(pmax, sv);
      }
    pmax = fmaxf(pmax, __shfl_xor(pmax, 16));
    pmax = fmaxf(pmax, __shfl_xor(pmax, 32));
    const float mnew  = fmaxf(mrun, pmax);
    const float alpha = __expf(mrun - mnew);
    float lsum = 0.f;
#pragma unroll
    for (int f = 0; f < 4; ++f)
#pragma unroll
      for (int r = 0; r < 4; ++r) {
        float p = __expf(s[f][r] - mnew);
        s[f][r] = p;
        lsum += p;
      }
    lsum += __shfl_xor(lsum, 16);
    lsum += __shfl_xor(lsum, 32);
    lrun = lrun * alpha + lsum;
    mrun = mnew;

#pragma unroll
    for (int f = 0; f < 4; ++f) {
      bf16x4 pk;
      pk[0] = (__bf16)s[f][0]; pk[1] = (__bf16)s[f][1];
      pk[2] = (__bf16)s[f][2]; pk[3] = (__bf16)s[f][3];
      *(bf16x4*)&Ps[w][l15][f * 16 + g * 4] = pk;
    }
    asm volatile("s_waitcnt lgkmcnt(0)" ::: "memory");

    float al[4];
#pragma unroll
    for (int r = 0; r < 4; ++r) al[r] = __shfl(alpha, g * 4 + r);
#pragma unroll
    for (int nf = 0; nf < 4; ++nf)
#pragma unroll
      for (int r = 0; r < 4; ++r) acc[nf][r] *= al[r];

#pragma unroll
    for (int ks = 0; ks < 2; ++ks) {
      bf16x8 pa = *(const bf16x8*)&Ps[w][l15][ks * 32 + g * 8];
#pragma unroll
      for (int nf = 0; nf < 4; ++nf) {
        bf16x8 vf = *(const bf16x8*)&VTs[nf * 16 + l15][ks * 32 + g * 8];
        acc[nf] = __builtin_amdgcn_mfma_f32_16x16x32_bf16(pa, vf, acc[nf], 0, 0, 0);
      }
    }
  }

  float li[4];
#pragma unroll
  for (int r = 0; r < 4; ++r) li[r] = 1.0f / __shfl(lrun, g * 4 + r);
#pragma unroll
  for (int nf = 0; nf < 4; ++nf)
#pragma unroll
    for (int r = 0; r < 4; ++r) {
      const int row = q0 + w * 16 + 4 * g + r;
      ctx[((size_t)(bb * 2048 + row)) * DD + hh * 64 + nf * 16 + l15] =
          (__bf16)(acc[nf][r] * li[r]);
    }
}

// ---------------- launcher ----------------
extern "C" void kernel_launch(void* const* d_in, const int* in_sizes, int n_in,
                              void* d_out, int out_size, void* d_ws, size_t ws_size,
                              hipStream_t stream)
{
  (void)in_sizes; (void)n_in; (void)out_size; (void)ws_size;
  const float* x  = (const float*)d_in[0];
  const float* wq = (const float*)d_in[1];
  const float* wk = (const float*)d_in[2];
  const float* wv = (const float*)d_in[3];
  const float* wo = (const float*)d_in[4];
  const float* bo = (const float*)d_in[5];
  const float* w1 = (const float*)d_in[6];
  const float* b1 = (const float*)d_in[7];
  const float* w2 = (const float*)d_in[8];
  const float* b2 = (const float*)d_in[9];
  const float* g1 = (const float*)d_in[10];
  const float* s1 = (const float*)d_in[11];
  const float* g2 = (const float*)d_in[12];
  const float* s2 = (const float*)d_in[13];
  float* out = (float*)d_out;

  char* ws = (char*)d_ws;
  __bf16* wbf  = (__bf16*)ws;                         // 24MB weights (q,k,v,o,w1,w2)
  __bf16* hbuf = (__bf16*)(ws + 25165824);            // 8MB
  __bf16* qkb  = (__bf16*)(ws + 33554432);            // 16MB, Q|K [4096][2048]
  __bf16* vbT  = (__bf16*)(ws + 50331648);            // 8MB,  V^T [2][16][64][2048]
  __bf16* ctxb = (__bf16*)(ws + 58720256);            // 8MB
  float*  x2   = (float*)(ws + 67108864);             // 16MB
  __bf16* ffb  = (__bf16*)(ws + 83886080);            // 32MB
  __bf16* part = (__bf16*)(ws + 33554432);            // 32MB, overlaps qkb..ctxb (dead post-WO)

  cvt_weights<<<12288, 256, 0, stream>>>(wq, wk, wv, wo, w1, w2, wbf);
  ln_kernel<<<1024, 256, 0, stream>>>(x, g1, s1, hbuf);

  // fused QKV: M=4096 N=3072 K=1024 (V transposed in epilogue)
  gemm256<0><<<dim3(12, 16), 512, 0, stream>>>(
      hbuf, 1024, wbf, 1024, qkb, nullptr, vbT, NTOK, 3072, 1024);

  dim3 ga(32, 16, 2);
  attn_kernel<<<ga, 256, 0, stream>>>(qkb, vbT, ctxb);

  // WO: M=4096 N=1024 K=1024 (+bo, +x residual, f32)
  gemm_bt<true, true><<<dim3(8, 32), 256, 0, stream>>>(
      ctxb, wbf + 3145728, x2, bo, x, NTOK, DD, DD);
  ln_kernel<<<1024, 256, 0, stream>>>(x2, g2, s2, hbuf);

  // FF1: M=4096 N=4096 K=1024, bias+gelu -> bf16
  gemm256<1><<<dim3(16, 16), 512, 0, stream>>>(
      hbuf, 1024, wbf + 4194304, 1024, ffb, b1, nullptr, NTOK, FFD, 1024);

  // FF2 split-K (KS=4): bf16 partials, then fused reduce (+b2, +x2)
  gemm256<2><<<dim3(4, 16, 4), 512, 0, stream>>>(
      ffb, 4096, wbf + 8388608, 4096, part, nullptr, nullptr, NTOK, DD, 1024);
  ff2_reduce<<<4096, 256, 0, stream>>>(part, x2, b2, out);
}

// Round 6
// 266.445 us; speedup vs baseline: 1.4034x; 1.0681x over previous
//
#include <hip/hip_runtime.h>
#include <hip/hip_bf16.h>
#include <stdint.h>

// TransformerBlock: B=2 T=2048 D=1024 H=16 HD=64 FF=4096, causal, pre-LN.
// GEMMs + attention in bf16 MFMA (16x16x32), f32 accum, f32 residual path.

typedef __attribute__((ext_vector_type(8))) __bf16 bf16x8;
typedef __attribute__((ext_vector_type(4))) __bf16 bf16x4;
typedef __attribute__((ext_vector_type(4))) float  f32x4;

#define DD    1024
#define TSEQ  2048
#define NTOK  4096
#define FFD   4096

#define ASM_VMCNT4() asm volatile("s_waitcnt vmcnt(4)" ::: "memory")
#define ASM_VMCNT0() asm volatile("s_waitcnt vmcnt(0)" ::: "memory")
#define ASM_LGKM0()  asm volatile("s_waitcnt lgkmcnt(0)" ::: "memory")

__device__ __forceinline__ void gll16(const void* g, void* l) {
  __builtin_amdgcn_global_load_lds(
      (const __attribute__((address_space(1))) unsigned int*)g,
      (__attribute__((address_space(3))) unsigned int*)l, 16, 0, 0);
}

__device__ __forceinline__ float gelu_f(float v) {
  float u = 0.7978845608028654f * (v + 0.044715f * v * v * v);
  float t = 1.0f - 2.0f / (1.0f + __expf(2.0f * u));   // tanh(u)
  return 0.5f * v * (1.0f + t);
}

// ---------------- weight f32 -> bf16 convert ----------------
__global__ __launch_bounds__(256) void cvt_weights(
    const float* __restrict__ wq, const float* __restrict__ wk,
    const float* __restrict__ wv, const float* __restrict__ wo,
    const float* __restrict__ w1, const float* __restrict__ w2,
    __bf16* __restrict__ dst)
{
  size_t i4 = (size_t)blockIdx.x * 256 + threadIdx.x;
  size_t e = i4 * 4;
  const float* src; size_t off;
  if (e < (size_t)4 * 1048576) {
    int sel = (int)(e >> 20);
    src = sel == 0 ? wq : sel == 1 ? wk : sel == 2 ? wv : wo;
    off = e & 1048575;
  } else if (e < (size_t)8 * 1048576) {
    src = w1; off = e - (size_t)4 * 1048576;
  } else {
    src = w2; off = e - (size_t)8 * 1048576;
  }
  float4 v = *(const float4*)(src + off);
  bf16x4 o;
  o[0] = (__bf16)v.x; o[1] = (__bf16)v.y; o[2] = (__bf16)v.z; o[3] = (__bf16)v.w;
  *(bf16x4*)(dst + e) = o;
}

// ---------------- LayerNorm: one wave per row ----------------
__global__ __launch_bounds__(256) void ln_kernel(
    const float* __restrict__ x, const float* __restrict__ gw,
    const float* __restrict__ sw, __bf16* __restrict__ out)
{
  const int row  = blockIdx.x * 4 + (threadIdx.x >> 6);
  const int lane = threadIdx.x & 63;
  const float4* xr = (const float4*)(x + (size_t)row * DD);
  float4 v[4];
  float s = 0.f, sq = 0.f;
#pragma unroll
  for (int i = 0; i < 4; ++i) {
    v[i] = xr[i * 64 + lane];
    s  += v[i].x + v[i].y + v[i].z + v[i].w;
    sq += v[i].x * v[i].x + v[i].y * v[i].y + v[i].z * v[i].z + v[i].w * v[i].w;
  }
#pragma unroll
  for (int off = 32; off >= 1; off >>= 1) {
    s  += __shfl_xor(s, off);
    sq += __shfl_xor(sq, off);
  }
  const float mean = s * (1.f / DD);
  const float rstd = rsqrtf(sq * (1.f / DD) - mean * mean + 1e-5f);
  const float4* gr = (const float4*)gw;
  const float4* sr = (const float4*)sw;
#pragma unroll
  for (int i = 0; i < 4; ++i) {
    float4 gv = gr[i * 64 + lane];
    float4 sv = sr[i * 64 + lane];
    bf16x4 o;
    o[0] = (__bf16)(gv.x * (v[i].x - mean) * rstd + sv.x);
    o[1] = (__bf16)(gv.y * (v[i].y - mean) * rstd + sv.y);
    o[2] = (__bf16)(gv.z * (v[i].z - mean) * rstd + sv.z);
    o[3] = (__bf16)(gv.w * (v[i].w - mean) * rstd + sv.w);
    *(bf16x4*)&out[(size_t)row * DD + (size_t)(i * 64 + lane) * 4] = o;
  }
}

// ================= 8-phase deep-pipelined 256x256 GEMM (m201 structure) =====
// C[M,N] = A[M,K(lda)] @ Bw[N,K(ldb)]^T. 512 thr / 8 waves (2x4), BK=64.
// 2x64KB LDS K-tile buffers. Per K-tile 4 phases, each:
//   {ds_read subtile; stage 1 half-tile (2 gll16); s_barrier; lgkmcnt(0);
//    sched_barrier; setprio(1); 16 MFMA (one C-quadrant); setprio(0); s_barrier}
// Staging stagger: A(kt+1) at P0/P1 (other buf), B(kt+2) at P2/P3 (cur buf,
// B-reads done by P1). vmcnt(4) once per K-tile at P3 (leaves next-B in flight).
// Chunk-XOR swizzle both-sides (conflict-free, verified 0 conflicts R5).
// MODE: 0=QKV (bf16, V transposed to voutT), 1=bias+gelu bf16, 2=bf16 partial.
template<int MODE>
__global__ __launch_bounds__(512, 2)
void gemm256(const __bf16* __restrict__ A, int lda,
             const __bf16* __restrict__ Bw, int ldb,
             __bf16* __restrict__ Cout, const float* __restrict__ bias,
             __bf16* __restrict__ voutT, int M, int N, int K)
{
  __shared__ __bf16 sm[65536];          // 2 bufs x (A 16384 + B 16384) elems
  const int t = threadIdx.x;
  const int lane = t & 63;
  const int l15 = lane & 15, g = lane >> 4;
  const int w = t >> 6;
  const int wm = w >> 2, wn = w & 3;    // 2 x 4 wave grid
  const int m0 = blockIdx.y * 256, n0 = blockIdx.x * 256;

  if (MODE == 2) {                      // split-K offsets
    const int kz = blockIdx.z;
    A    += (size_t)kz * 1024;
    Bw   += (size_t)kz * 1024;
    Cout += (size_t)kz * (size_t)M * N;
  }

  // stage one half-tile (128 rows x 64 cols) of A or B: 2 gll16 per thread.
  // LDS dest linear in lane order; global source chunk pre-XOR'd (m201 pattern).
  auto STAGE_A = [&](int kt, int h, int b) {
#pragma unroll
    for (int i = 0; i < 2; ++i) {
      const int slot = i * 512 + t;
      const int row  = h * 128 + (slot >> 3);
      const int gc   = (slot & 7) ^ (row & 7);
      gll16(A + (size_t)(m0 + row) * lda + kt * 64 + gc * 8,
            sm + b * 32768 + h * 8192 + slot * 8);
    }
  };
  auto STAGE_B = [&](int kt, int h, int b) {
#pragma unroll
    for (int i = 0; i < 2; ++i) {
      const int slot = i * 512 + t;
      const int row  = h * 128 + (slot >> 3);
      const int gc   = (slot & 7) ^ (row & 7);
      gll16(Bw + (size_t)(n0 + row) * ldb + kt * 64 + gc * 8,
            sm + b * 32768 + 16384 + h * 8192 + slot * 8);
    }
  };

  f32x4 acc[8][4] = {};
  const int NT = K >> 6;

  // prologue: tile0 full (8 loads) + tile1 B-halves (4 loads)
  STAGE_A(0, 0, 0); STAGE_A(0, 1, 0);
  STAGE_B(0, 0, 0); STAGE_B(0, 1, 0);
  STAGE_B(1, 0, 1); STAGE_B(1, 1, 1);
  ASM_VMCNT4();                          // tile0 landed
  __builtin_amdgcn_s_barrier();

  for (int kt = 0; kt < NT; ++kt) {
    const int cb = kt & 1;
    const __bf16* sA = sm + cb * 32768;
    const __bf16* sB = sm + cb * 32768 + 16384;
    const bool pf1 = (kt + 1 < NT);
    const bool pf2 = (kt + 2 < NT);

    bf16x8 afl[4][2], afh[4][2], bfl[2][2], bfh[2][2];

    // ---------------- P0: read afl(mi0-3)+bfl(ni0-1); stage A0(kt+1) --------
#pragma unroll
    for (int mi = 0; mi < 4; ++mi) {
      const int row = wm * 128 + mi * 16 + l15;
#pragma unroll
      for (int ks = 0; ks < 2; ++ks)
        afl[mi][ks] = *(const bf16x8*)&sA[row * 64 + (((ks * 4 + g) ^ (row & 7)) * 8)];
    }
#pragma unroll
    for (int ni = 0; ni < 2; ++ni) {
      const int row = wn * 64 + ni * 16 + l15;
#pragma unroll
      for (int ks = 0; ks < 2; ++ks)
        bfl[ni][ks] = *(const bf16x8*)&sB[row * 64 + (((ks * 4 + g) ^ (row & 7)) * 8)];
    }
    if (pf1) STAGE_A(kt + 1, 0, cb ^ 1);
    __builtin_amdgcn_s_barrier();
    ASM_LGKM0();
    __builtin_amdgcn_sched_barrier(0);
    __builtin_amdgcn_s_setprio(1);
#pragma unroll
    for (int ks = 0; ks < 2; ++ks)
#pragma unroll
      for (int mi = 0; mi < 4; ++mi)
#pragma unroll
        for (int ni = 0; ni < 2; ++ni)
          acc[mi][ni] = __builtin_amdgcn_mfma_f32_16x16x32_bf16(
              afl[mi][ks], bfl[ni][ks], acc[mi][ni], 0, 0, 0);
    __builtin_amdgcn_s_setprio(0);
    __builtin_amdgcn_s_barrier();

    // ---------------- P1: read bfh(ni2-3); stage A1(kt+1) -------------------
#pragma unroll
    for (int ni = 0; ni < 2; ++ni) {
      const int row = wn * 64 + (ni + 2) * 16 + l15;
#pragma unroll
      for (int ks = 0; ks < 2; ++ks)
        bfh[ni][ks] = *(const bf16x8*)&sB[row * 64 + (((ks * 4 + g) ^ (row & 7)) * 8)];
    }
    if (pf1) STAGE_A(kt + 1, 1, cb ^ 1);
    __builtin_amdgcn_s_barrier();
    ASM_LGKM0();
    __builtin_amdgcn_sched_barrier(0);
    __builtin_amdgcn_s_setprio(1);
#pragma unroll
    for (int ks = 0; ks < 2; ++ks)
#pragma unroll
      for (int mi = 0; mi < 4; ++mi)
#pragma unroll
        for (int ni = 0; ni < 2; ++ni)
          acc[mi][ni + 2] = __builtin_amdgcn_mfma_f32_16x16x32_bf16(
              afl[mi][ks], bfh[ni][ks], acc[mi][ni + 2], 0, 0, 0);
    __builtin_amdgcn_s_setprio(0);
    __builtin_amdgcn_s_barrier();

    // ---------------- P2: read afh(mi4-7); stage B0(kt+2) -------------------
#pragma unroll
    for (int mi = 0; mi < 4; ++mi) {
      const int row = wm * 128 + (mi + 4) * 16 + l15;
#pragma unroll
      for (int ks = 0; ks < 2; ++ks)
        afh[mi][ks] = *(const bf16x8*)&sA[row * 64 + (((ks * 4 + g) ^ (row & 7)) * 8)];
    }
    if (pf2) STAGE_B(kt + 2, 0, cb);
    __builtin_amdgcn_s_barrier();
    ASM_LGKM0();
    __builtin_amdgcn_sched_barrier(0);
    __builtin_amdgcn_s_setprio(1);
#pragma unroll
    for (int ks = 0; ks < 2; ++ks)
#pragma unroll
      for (int mi = 0; mi < 4; ++mi)
#pragma unroll
        for (int ni = 0; ni < 2; ++ni)
          acc[mi + 4][ni + 2] = __builtin_amdgcn_mfma_f32_16x16x32_bf16(
              afh[mi][ks], bfh[ni][ks], acc[mi + 4][ni + 2], 0, 0, 0);
    __builtin_amdgcn_s_setprio(0);
    __builtin_amdgcn_s_barrier();

    // ---------------- P3: stage B1(kt+2); MFMA Q3; vmcnt(4) -----------------
    if (pf2) STAGE_B(kt + 2, 1, cb);
    __builtin_amdgcn_s_barrier();
    __builtin_amdgcn_s_setprio(1);
#pragma unroll
    for (int ks = 0; ks < 2; ++ks)
#pragma unroll
      for (int mi = 0; mi < 4; ++mi)
#pragma unroll
        for (int ni = 0; ni < 2; ++ni)
          acc[mi + 4][ni] = __builtin_amdgcn_mfma_f32_16x16x32_bf16(
              afh[mi][ks], bfl[ni][ks], acc[mi + 4][ni], 0, 0, 0);
    __builtin_amdgcn_s_setprio(0);
    if (pf1) { if (pf2) ASM_VMCNT4(); else ASM_VMCNT0(); }
    __builtin_amdgcn_s_barrier();
  }

  // epilogue: C/D frag layout col = lane&15, row = 4*(lane>>4)+r
#pragma unroll
  for (int mi = 0; mi < 8; ++mi) {
    const int rr0 = m0 + wm * 128 + mi * 16 + 4 * g;
#pragma unroll
    for (int ni = 0; ni < 4; ++ni) {
      const int cc = n0 + wn * 64 + ni * 16 + l15;
      if (MODE == 0 && n0 + wn * 64 >= 2048) {
        // V: write transposed vT[b][h][d][t], 4 consecutive tokens vectorized
        const int b  = rr0 >> 11;
        const int t0 = rr0 & 2047;
        const int vc = cc - 2048;
        const int h = vc >> 6, d = vc & 63;
        bf16x4 o;
        o[0] = (__bf16)acc[mi][ni][0]; o[1] = (__bf16)acc[mi][ni][1];
        o[2] = (__bf16)acc[mi][ni][2]; o[3] = (__bf16)acc[mi][ni][3];
        *(bf16x4*)&voutT[(((size_t)(b * 16 + h)) * 64 + d) * 2048 + t0] = o;
      } else {
        const int ldc = (MODE == 0) ? 2048 : N;
#pragma unroll
        for (int r = 0; r < 4; ++r) {
          float v = acc[mi][ni][r];
          if (MODE == 1) { v += bias[cc]; v = gelu_f(v); }
          Cout[(size_t)(rr0 + r) * ldc + cc] = (__bf16)v;
        }
      }
    }
  }
}

// ---------------- FF2 reduce: out = x2 + b2 + sum(partials) ----------------
// out has 4,194,304 elements; 256 thr x 4 elems -> EXACTLY 4096 blocks.
__global__ __launch_bounds__(256) void ff2_reduce(
    const __bf16* __restrict__ part, const float* __restrict__ x2,
    const float* __restrict__ b2, float* __restrict__ out)
{
  const size_t e = ((size_t)blockIdx.x * 256 + threadIdx.x) * 4;
  float4 r = *(const float4*)(x2 + e);
  const float4 b = *(const float4*)(b2 + (e & 1023));
  r.x += b.x; r.y += b.y; r.z += b.z; r.w += b.w;
#pragma unroll
  for (int s = 0; s < 4; ++s) {
    bf16x4 p = *(const bf16x4*)(part + (size_t)s * 4194304 + e);
    r.x += (float)p[0]; r.y += (float)p[1]; r.z += (float)p[2]; r.w += (float)p[3];
  }
  *(float4*)(out + e) = r;
}

// ---------------- legacy 128x128 GEMM (WO only) ----------------
template<bool BIAS, bool RES>
__global__ __launch_bounds__(256, 3)
void gemm_bt(const __bf16* __restrict__ A, const __bf16* __restrict__ Bw,
             float* __restrict__ Cout, const float* __restrict__ bias,
             const float* __restrict__ res, int M, int N, int K)
{
  __shared__ __bf16 As[128 * 64];
  __shared__ __bf16 Bs[128 * 64];
  const int t    = threadIdx.x;
  const int lane = t & 63;
  const int l15  = lane & 15;
  const int g    = lane >> 4;
  const int w    = t >> 6;
  const int wr   = w >> 1, wc = w & 1;
  const int m0 = blockIdx.y * 128;
  const int n0 = blockIdx.x * 128;
  const int srow = t >> 3;
  const int scol = (t & 7) * 8;

  f32x4 acc[4][4] = {};
  const __bf16* Ap = A  + (size_t)m0 * K;
  const __bf16* Bp = Bw + (size_t)n0 * K;

  for (int k0 = 0; k0 < K; k0 += 64) {
#pragma unroll
    for (int i = 0; i < 4; ++i) {
      const int row = i * 32 + srow;
      gll16(Ap + (size_t)row * K + k0 + scol, &As[row * 64 + scol]);
    }
#pragma unroll
    for (int i = 0; i < 4; ++i) {
      const int row = i * 32 + srow;
      gll16(Bp + (size_t)row * K + k0 + scol, &Bs[row * 64 + scol]);
    }
    __syncthreads();
#pragma unroll
    for (int ks = 0; ks < 2; ++ks) {
      bf16x8 af[4], bfr[4];
#pragma unroll
      for (int mi = 0; mi < 4; ++mi)
        af[mi] = *(const bf16x8*)&As[(wr * 64 + mi * 16 + l15) * 64 + ks * 32 + g * 8];
#pragma unroll
      for (int ni = 0; ni < 4; ++ni)
        bfr[ni] = *(const bf16x8*)&Bs[(wc * 64 + ni * 16 + l15) * 64 + ks * 32 + g * 8];
#pragma unroll
      for (int mi = 0; mi < 4; ++mi)
#pragma unroll
        for (int ni = 0; ni < 4; ++ni)
          acc[mi][ni] = __builtin_amdgcn_mfma_f32_16x16x32_bf16(af[mi], bfr[ni], acc[mi][ni], 0, 0, 0);
    }
    __syncthreads();
  }

  const int crow0 = m0 + wr * 64;
  const int ccol0 = n0 + wc * 64;
#pragma unroll
  for (int mi = 0; mi < 4; ++mi) {
#pragma unroll
    for (int r = 0; r < 4; ++r) {
      const int rr = crow0 + mi * 16 + 4 * g + r;
#pragma unroll
      for (int ni = 0; ni < 4; ++ni) {
        const int cc = ccol0 + ni * 16 + l15;
        float v = acc[mi][ni][r];
        if (BIAS) v += bias[cc];
        if (RES)  v += res[(size_t)rr * N + cc];
        Cout[(size_t)rr * N + cc] = v;
      }
    }
  }
}

// ---------------- causal flash attention ----------------
__global__ __launch_bounds__(256, 2)
void attn_kernel(const __bf16* __restrict__ qk, const __bf16* __restrict__ vT,
                 __bf16* __restrict__ ctx)
{
  __shared__ __bf16 Ks[64][72];
  __shared__ __bf16 VTs[64][72];
  __shared__ __bf16 Ps[4][16][72];
  const int t    = threadIdx.x;
  const int lane = t & 63;
  const int l15  = lane & 15;
  const int g    = lane >> 4;
  const int w    = t >> 6;
  const int qt = gridDim.x - 1 - blockIdx.x;
  const int hh = blockIdx.y;
  const int bb = blockIdx.z;
  const int q0 = qt * 64;

  const int qrow = q0 + w * 16 + l15;
  const size_t qkrow = ((size_t)(bb * 2048 + qrow)) * 2048 + hh * 64;
  bf16x8 qf[2];
  qf[0] = *(const bf16x8*)&qk[qkrow + g * 8];
  qf[1] = *(const bf16x8*)&qk[qkrow + 32 + g * 8];

  f32x4 acc[4] = {};
  float mrun = -1e30f, lrun = 0.f;

  for (int kt = 0; kt <= qt; ++kt) {
    __syncthreads();
    {
      const int kk = t >> 2;
      const int d0 = (t & 3) * 16;
      const __bf16* krow = &qk[((size_t)(bb * 2048 + kt * 64 + kk)) * 2048 + 1024 + hh * 64];
      *(bf16x8*)&Ks[kk][d0]     = *(const bf16x8*)&krow[d0];
      *(bf16x8*)&Ks[kk][d0 + 8] = *(const bf16x8*)&krow[d0 + 8];
      const __bf16* vrow = &vT[(((size_t)(bb * 16 + hh)) * 64 + kk) * 2048 + kt * 64 + d0];
      *(bf16x8*)&VTs[kk][d0]     = *(const bf16x8*)&vrow[0];
      *(bf16x8*)&VTs[kk][d0 + 8] = *(const bf16x8*)&vrow[8];
    }
    __syncthreads();

    f32x4 s[4];
#pragma unroll
    for (int f = 0; f < 4; ++f) {
      f32x4 z = {};
      bf16x8 a0 = *(const bf16x8*)&Ks[f * 16 + l15][g * 8];
      bf16x8 a1 = *(const bf16x8*)&Ks[f * 16 + l15][32 + g * 8];
      z = __builtin_amdgcn_mfma_f32_16x16x32_bf16(a0, qf[0], z, 0, 0, 0);
      z = __builtin_amdgcn_mfma_f32_16x16x32_bf16(a1, qf[1], z, 0, 0, 0);
      s[f] = z;
    }

    const int qg = q0 + w * 16 + l15;
    float pmax = -1e30f;
#pragma unroll
    for (int f = 0; f < 4; ++f)
#pragma unroll
      for (int r = 0; r < 4; ++r) {
        float sv = s[f][r] * 0.125f;
        const int kg = kt * 64 + f * 16 + g * 4 + r;
        if (kg > qg) sv = -1e30f;
        s[f][r] = sv;
        pmax = fmaxf(pmax, sv);
      }
    pmax = fmaxf(pmax, __shfl_xor(pmax, 16));
    pmax = fmaxf(pmax, __shfl_xor(pmax, 32));
    const float mnew  = fmaxf(mrun, pmax);
    const float alpha = __expf(mrun - mnew);
    float lsum = 0.f;
#pragma unroll
    for (int f = 0; f < 4; ++f)
#pragma unroll
      for (int r = 0; r < 4; ++r) {
        float p = __expf(s[f][r] - mnew);
        s[f][r] = p;
        lsum += p;
      }
    lsum += __shfl_xor(lsum, 16);
    lsum += __shfl_xor(lsum, 32);
    lrun = lrun * alpha + lsum;
    mrun = mnew;

#pragma unroll
    for (int f = 0; f < 4; ++f) {
      bf16x4 pk;
      pk[0] = (__bf16)s[f][0]; pk[1] = (__bf16)s[f][1];
      pk[2] = (__bf16)s[f][2]; pk[3] = (__bf16)s[f][3];
      *(bf16x4*)&Ps[w][l15][f * 16 + g * 4] = pk;
    }
    asm volatile("s_waitcnt lgkmcnt(0)" ::: "memory");

    float al[4];
#pragma unroll
    for (int r = 0; r < 4; ++r) al[r] = __shfl(alpha, g * 4 + r);
#pragma unroll
    for (int nf = 0; nf < 4; ++nf)
#pragma unroll
      for (int r = 0; r < 4; ++r) acc[nf][r] *= al[r];

#pragma unroll
    for (int ks = 0; ks < 2; ++ks) {
      bf16x8 pa = *(const bf16x8*)&Ps[w][l15][ks * 32 + g * 8];
#pragma unroll
      for (int nf = 0; nf < 4; ++nf) {
        bf16x8 vf = *(const bf16x8*)&VTs[nf * 16 + l15][ks * 32 + g * 8];
        acc[nf] = __builtin_amdgcn_mfma_f32_16x16x32_bf16(pa, vf, acc[nf], 0, 0, 0);
      }
    }
  }

  float li[4];
#pragma unroll
  for (int r = 0; r < 4; ++r) li[r] = 1.0f / __shfl(lrun, g * 4 + r);
#pragma unroll
  for (int nf = 0; nf < 4; ++nf)
#pragma unroll
    for (int r = 0; r < 4; ++r) {
      const int row = q0 + w * 16 + 4 * g + r;
      ctx[((size_t)(bb * 2048 + row)) * DD + hh * 64 + nf * 16 + l15] =
          (__bf16)(acc[nf][r] * li[r]);
    }
}

// ---------------- launcher ----------------
extern "C" void kernel_launch(void* const* d_in, const int* in_sizes, int n_in,
                              void* d_out, int out_size, void* d_ws, size_t ws_size,
                              hipStream_t stream)
{
  (void)in_sizes; (void)n_in; (void)out_size; (void)ws_size;
  const float* x  = (const float*)d_in[0];
  const float* wq = (const float*)d_in[1];
  const float* wk = (const float*)d_in[2];
  const float* wv = (const float*)d_in[3];
  const float* wo = (const float*)d_in[4];
  const float* bo = (const float*)d_in[5];
  const float* w1 = (const float*)d_in[6];
  const float* b1 = (const float*)d_in[7];
  const float* w2 = (const float*)d_in[8];
  const float* b2 = (const float*)d_in[9];
  const float* g1 = (const float*)d_in[10];
  const float* s1 = (const float*)d_in[11];
  const float* g2 = (const float*)d_in[12];
  const float* s2 = (const float*)d_in[13];
  float* out = (float*)d_out;

  char* ws = (char*)d_ws;
  __bf16* wbf  = (__bf16*)ws;                         // 24MB weights (q,k,v,o,w1,w2)
  __bf16* hbuf = (__bf16*)(ws + 25165824);            // 8MB
  __bf16* qkb  = (__bf16*)(ws + 33554432);            // 16MB, Q|K [4096][2048]
  __bf16* vbT  = (__bf16*)(ws + 50331648);            // 8MB,  V^T [2][16][64][2048]
  __bf16* ctxb = (__bf16*)(ws + 58720256);            // 8MB
  float*  x2   = (float*)(ws + 67108864);             // 16MB
  __bf16* ffb  = (__bf16*)(ws + 83886080);            // 32MB
  __bf16* part = (__bf16*)(ws + 33554432);            // 32MB, overlaps qkb..ctxb (dead post-WO)

  cvt_weights<<<12288, 256, 0, stream>>>(wq, wk, wv, wo, w1, w2, wbf);
  ln_kernel<<<1024, 256, 0, stream>>>(x, g1, s1, hbuf);

  // fused QKV: M=4096 N=3072 K=1024 (V transposed in epilogue)
  gemm256<0><<<dim3(12, 16), 512, 0, stream>>>(
      hbuf, 1024, wbf, 1024, qkb, nullptr, vbT, NTOK, 3072, 1024);

  dim3 ga(32, 16, 2);
  attn_kernel<<<ga, 256, 0, stream>>>(qkb, vbT, ctxb);

  // WO: M=4096 N=1024 K=1024 (+bo, +x residual, f32)
  gemm_bt<true, true><<<dim3(8, 32), 256, 0, stream>>>(
      ctxb, wbf + 3145728, x2, bo, x, NTOK, DD, DD);
  ln_kernel<<<1024, 256, 0, stream>>>(x2, g2, s2, hbuf);

  // FF1: M=4096 N=4096 K=1024, bias+gelu -> bf16
  gemm256<1><<<dim3(16, 16), 512, 0, stream>>>(
      hbuf, 1024, wbf + 4194304, 1024, ffb, b1, nullptr, NTOK, FFD, 1024);

  // FF2 split-K (KS=4): bf16 partials, then fused reduce (+b2, +x2)
  gemm256<2><<<dim3(4, 16, 4), 512, 0, stream>>>(
      ffb, 4096, wbf + 8388608, 4096, part, nullptr, nullptr, NTOK, DD, 1024);
  ff2_reduce<<<4096, 256, 0, stream>>>(part, x2, b2, out);
}

// Round 7
// 241.830 us; speedup vs baseline: 1.5462x; 1.1018x over previous
//
#include <hip/hip_runtime.h>
#include <hip/hip_bf16.h>
#include <stdint.h>

// TransformerBlock: B=2 T=2048 D=1024 H=16 HD=64 FF=4096, causal, pre-LN.
// GEMMs + attention in bf16 MFMA (16x16x32), f32 accum, f32 residual path.

typedef __attribute__((ext_vector_type(8))) __bf16 bf16x8;
typedef __attribute__((ext_vector_type(4))) __bf16 bf16x4;
typedef __attribute__((ext_vector_type(4))) float  f32x4;

#define DD    1024
#define TSEQ  2048
#define NTOK  4096
#define FFD   4096

#define ASM_VMCNT4() asm volatile("s_waitcnt vmcnt(4)" ::: "memory")
#define ASM_VMCNT0() asm volatile("s_waitcnt vmcnt(0)" ::: "memory")
#define ASM_LGKM0()  asm volatile("s_waitcnt lgkmcnt(0)" ::: "memory")

__device__ __forceinline__ void gll16(const void* g, void* l) {
  __builtin_amdgcn_global_load_lds(
      (const __attribute__((address_space(1))) unsigned int*)g,
      (__attribute__((address_space(3))) unsigned int*)l, 16, 0, 0);
}

__device__ __forceinline__ float gelu_f(float v) {
  float u = 0.7978845608028654f * (v + 0.044715f * v * v * v);
  float t = 1.0f - 2.0f / (1.0f + __expf(2.0f * u));   // tanh(u)
  return 0.5f * v * (1.0f + t);
}

// ---------------- weight f32 -> bf16 convert ----------------
__global__ __launch_bounds__(256) void cvt_weights(
    const float* __restrict__ wq, const float* __restrict__ wk,
    const float* __restrict__ wv, const float* __restrict__ wo,
    const float* __restrict__ w1, const float* __restrict__ w2,
    __bf16* __restrict__ dst)
{
  size_t i4 = (size_t)blockIdx.x * 256 + threadIdx.x;
  size_t e = i4 * 4;
  const float* src; size_t off;
  if (e < (size_t)4 * 1048576) {
    int sel = (int)(e >> 20);
    src = sel == 0 ? wq : sel == 1 ? wk : sel == 2 ? wv : wo;
    off = e & 1048575;
  } else if (e < (size_t)8 * 1048576) {
    src = w1; off = e - (size_t)4 * 1048576;
  } else {
    src = w2; off = e - (size_t)8 * 1048576;
  }
  float4 v = *(const float4*)(src + off);
  bf16x4 o;
  o[0] = (__bf16)v.x; o[1] = (__bf16)v.y; o[2] = (__bf16)v.z; o[3] = (__bf16)v.w;
  *(bf16x4*)(dst + e) = o;
}

// ---------------- LayerNorm: one wave per row ----------------
__global__ __launch_bounds__(256) void ln_kernel(
    const float* __restrict__ x, const float* __restrict__ gw,
    const float* __restrict__ sw, __bf16* __restrict__ out)
{
  const int row  = blockIdx.x * 4 + (threadIdx.x >> 6);
  const int lane = threadIdx.x & 63;
  const float4* xr = (const float4*)(x + (size_t)row * DD);
  float4 v[4];
  float s = 0.f, sq = 0.f;
#pragma unroll
  for (int i = 0; i < 4; ++i) {
    v[i] = xr[i * 64 + lane];
    s  += v[i].x + v[i].y + v[i].z + v[i].w;
    sq += v[i].x * v[i].x + v[i].y * v[i].y + v[i].z * v[i].z + v[i].w * v[i].w;
  }
#pragma unroll
  for (int off = 32; off >= 1; off >>= 1) {
    s  += __shfl_xor(s, off);
    sq += __shfl_xor(sq, off);
  }
  const float mean = s * (1.f / DD);
  const float rstd = rsqrtf(sq * (1.f / DD) - mean * mean + 1e-5f);
  const float4* gr = (const float4*)gw;
  const float4* sr = (const float4*)sw;
#pragma unroll
  for (int i = 0; i < 4; ++i) {
    float4 gv = gr[i * 64 + lane];
    float4 sv = sr[i * 64 + lane];
    bf16x4 o;
    o[0] = (__bf16)(gv.x * (v[i].x - mean) * rstd + sv.x);
    o[1] = (__bf16)(gv.y * (v[i].y - mean) * rstd + sv.y);
    o[2] = (__bf16)(gv.z * (v[i].z - mean) * rstd + sv.z);
    o[3] = (__bf16)(gv.w * (v[i].w - mean) * rstd + sv.w);
    *(bf16x4*)&out[(size_t)row * DD + (size_t)(i * 64 + lane) * 4] = o;
  }
}

// ================= 8-phase deep-pipelined 256x256 GEMM (m201 structure) =====
// (unchanged from R6 except: MODE 0 pre-scales Q columns by 0.125)
template<int MODE>
__global__ __launch_bounds__(512, 2)
void gemm256(const __bf16* __restrict__ A, int lda,
             const __bf16* __restrict__ Bw, int ldb,
             __bf16* __restrict__ Cout, const float* __restrict__ bias,
             __bf16* __restrict__ voutT, int M, int N, int K)
{
  __shared__ __bf16 sm[65536];          // 2 bufs x (A 16384 + B 16384) elems
  const int t = threadIdx.x;
  const int lane = t & 63;
  const int l15 = lane & 15, g = lane >> 4;
  const int w = t >> 6;
  const int wm = w >> 2, wn = w & 3;    // 2 x 4 wave grid
  const int m0 = blockIdx.y * 256, n0 = blockIdx.x * 256;

  if (MODE == 2) {                      // split-K offsets
    const int kz = blockIdx.z;
    A    += (size_t)kz * 1024;
    Bw   += (size_t)kz * 1024;
    Cout += (size_t)kz * (size_t)M * N;
  }

  auto STAGE_A = [&](int kt, int h, int b) {
#pragma unroll
    for (int i = 0; i < 2; ++i) {
      const int slot = i * 512 + t;
      const int row  = h * 128 + (slot >> 3);
      const int gc   = (slot & 7) ^ (row & 7);
      gll16(A + (size_t)(m0 + row) * lda + kt * 64 + gc * 8,
            sm + b * 32768 + h * 8192 + slot * 8);
    }
  };
  auto STAGE_B = [&](int kt, int h, int b) {
#pragma unroll
    for (int i = 0; i < 2; ++i) {
      const int slot = i * 512 + t;
      const int row  = h * 128 + (slot >> 3);
      const int gc   = (slot & 7) ^ (row & 7);
      gll16(Bw + (size_t)(n0 + row) * ldb + kt * 64 + gc * 8,
            sm + b * 32768 + 16384 + h * 8192 + slot * 8);
    }
  };

  f32x4 acc[8][4] = {};
  const int NT = K >> 6;

  STAGE_A(0, 0, 0); STAGE_A(0, 1, 0);
  STAGE_B(0, 0, 0); STAGE_B(0, 1, 0);
  STAGE_B(1, 0, 1); STAGE_B(1, 1, 1);
  ASM_VMCNT4();
  __builtin_amdgcn_s_barrier();

  for (int kt = 0; kt < NT; ++kt) {
    const int cb = kt & 1;
    const __bf16* sA = sm + cb * 32768;
    const __bf16* sB = sm + cb * 32768 + 16384;
    const bool pf1 = (kt + 1 < NT);
    const bool pf2 = (kt + 2 < NT);

    bf16x8 afl[4][2], afh[4][2], bfl[2][2], bfh[2][2];

    // P0
#pragma unroll
    for (int mi = 0; mi < 4; ++mi) {
      const int row = wm * 128 + mi * 16 + l15;
#pragma unroll
      for (int ks = 0; ks < 2; ++ks)
        afl[mi][ks] = *(const bf16x8*)&sA[row * 64 + (((ks * 4 + g) ^ (row & 7)) * 8)];
    }
#pragma unroll
    for (int ni = 0; ni < 2; ++ni) {
      const int row = wn * 64 + ni * 16 + l15;
#pragma unroll
      for (int ks = 0; ks < 2; ++ks)
        bfl[ni][ks] = *(const bf16x8*)&sB[row * 64 + (((ks * 4 + g) ^ (row & 7)) * 8)];
    }
    if (pf1) STAGE_A(kt + 1, 0, cb ^ 1);
    __builtin_amdgcn_s_barrier();
    ASM_LGKM0();
    __builtin_amdgcn_sched_barrier(0);
    __builtin_amdgcn_s_setprio(1);
#pragma unroll
    for (int ks = 0; ks < 2; ++ks)
#pragma unroll
      for (int mi = 0; mi < 4; ++mi)
#pragma unroll
        for (int ni = 0; ni < 2; ++ni)
          acc[mi][ni] = __builtin_amdgcn_mfma_f32_16x16x32_bf16(
              afl[mi][ks], bfl[ni][ks], acc[mi][ni], 0, 0, 0);
    __builtin_amdgcn_s_setprio(0);
    __builtin_amdgcn_s_barrier();

    // P1
#pragma unroll
    for (int ni = 0; ni < 2; ++ni) {
      const int row = wn * 64 + (ni + 2) * 16 + l15;
#pragma unroll
      for (int ks = 0; ks < 2; ++ks)
        bfh[ni][ks] = *(const bf16x8*)&sB[row * 64 + (((ks * 4 + g) ^ (row & 7)) * 8)];
    }
    if (pf1) STAGE_A(kt + 1, 1, cb ^ 1);
    __builtin_amdgcn_s_barrier();
    ASM_LGKM0();
    __builtin_amdgcn_sched_barrier(0);
    __builtin_amdgcn_s_setprio(1);
#pragma unroll
    for (int ks = 0; ks < 2; ++ks)
#pragma unroll
      for (int mi = 0; mi < 4; ++mi)
#pragma unroll
        for (int ni = 0; ni < 2; ++ni)
          acc[mi][ni + 2] = __builtin_amdgcn_mfma_f32_16x16x32_bf16(
              afl[mi][ks], bfh[ni][ks], acc[mi][ni + 2], 0, 0, 0);
    __builtin_amdgcn_s_setprio(0);
    __builtin_amdgcn_s_barrier();

    // P2
#pragma unroll
    for (int mi = 0; mi < 4; ++mi) {
      const int row = wm * 128 + (mi + 4) * 16 + l15;
#pragma unroll
      for (int ks = 0; ks < 2; ++ks)
        afh[mi][ks] = *(const bf16x8*)&sA[row * 64 + (((ks * 4 + g) ^ (row & 7)) * 8)];
    }
    if (pf2) STAGE_B(kt + 2, 0, cb);
    __builtin_amdgcn_s_barrier();
    ASM_LGKM0();
    __builtin_amdgcn_sched_barrier(0);
    __builtin_amdgcn_s_setprio(1);
#pragma unroll
    for (int ks = 0; ks < 2; ++ks)
#pragma unroll
      for (int mi = 0; mi < 4; ++mi)
#pragma unroll
        for (int ni = 0; ni < 2; ++ni)
          acc[mi + 4][ni + 2] = __builtin_amdgcn_mfma_f32_16x16x32_bf16(
              afh[mi][ks], bfh[ni][ks], acc[mi + 4][ni + 2], 0, 0, 0);
    __builtin_amdgcn_s_setprio(0);
    __builtin_amdgcn_s_barrier();

    // P3
    if (pf2) STAGE_B(kt + 2, 1, cb);
    __builtin_amdgcn_s_barrier();
    __builtin_amdgcn_s_setprio(1);
#pragma unroll
    for (int ks = 0; ks < 2; ++ks)
#pragma unroll
      for (int mi = 0; mi < 4; ++mi)
#pragma unroll
        for (int ni = 0; ni < 2; ++ni)
          acc[mi + 4][ni] = __builtin_amdgcn_mfma_f32_16x16x32_bf16(
              afh[mi][ks], bfl[ni][ks], acc[mi + 4][ni], 0, 0, 0);
    __builtin_amdgcn_s_setprio(0);
    if (pf1) { if (pf2) ASM_VMCNT4(); else ASM_VMCNT0(); }
    __builtin_amdgcn_s_barrier();
  }

  // epilogue
#pragma unroll
  for (int mi = 0; mi < 8; ++mi) {
    const int rr0 = m0 + wm * 128 + mi * 16 + 4 * g;
#pragma unroll
    for (int ni = 0; ni < 4; ++ni) {
      const int cc = n0 + wn * 64 + ni * 16 + l15;
      if (MODE == 0 && n0 + wn * 64 >= 2048) {
        const int b  = rr0 >> 11;
        const int t0 = rr0 & 2047;
        const int vc = cc - 2048;
        const int h = vc >> 6, d = vc & 63;
        bf16x4 o;
        o[0] = (__bf16)acc[mi][ni][0]; o[1] = (__bf16)acc[mi][ni][1];
        o[2] = (__bf16)acc[mi][ni][2]; o[3] = (__bf16)acc[mi][ni][3];
        *(bf16x4*)&voutT[(((size_t)(b * 16 + h)) * 64 + d) * 2048 + t0] = o;
      } else {
        const int ldc = (MODE == 0) ? 2048 : N;
#pragma unroll
        for (int r = 0; r < 4; ++r) {
          float v = acc[mi][ni][r];
          if (MODE == 0 && cc < 1024) v *= 0.125f;   // fold 1/sqrt(HD) into Q
          if (MODE == 1) { v += bias[cc]; v = gelu_f(v); }
          Cout[(size_t)(rr0 + r) * ldc + cc] = (__bf16)v;
        }
      }
    }
  }
}

// ---------------- FF2 reduce: out = x2 + b2 + sum(partials) ----------------
__global__ __launch_bounds__(256) void ff2_reduce(
    const __bf16* __restrict__ part, const float* __restrict__ x2,
    const float* __restrict__ b2, float* __restrict__ out)
{
  const size_t e = ((size_t)blockIdx.x * 256 + threadIdx.x) * 4;
  float4 r = *(const float4*)(x2 + e);
  const float4 b = *(const float4*)(b2 + (e & 1023));
  r.x += b.x; r.y += b.y; r.z += b.z; r.w += b.w;
#pragma unroll
  for (int s = 0; s < 4; ++s) {
    bf16x4 p = *(const bf16x4*)(part + (size_t)s * 4194304 + e);
    r.x += (float)p[0]; r.y += (float)p[1]; r.z += (float)p[2]; r.w += (float)p[3];
  }
  *(float4*)(out + e) = r;
}

// ---------------- legacy 128x128 GEMM (WO only) ----------------
template<bool BIAS, bool RES>
__global__ __launch_bounds__(256, 3)
void gemm_bt(const __bf16* __restrict__ A, const __bf16* __restrict__ Bw,
             float* __restrict__ Cout, const float* __restrict__ bias,
             const float* __restrict__ res, int M, int N, int K)
{
  __shared__ __bf16 As[128 * 64];
  __shared__ __bf16 Bs[128 * 64];
  const int t    = threadIdx.x;
  const int lane = t & 63;
  const int l15  = lane & 15;
  const int g    = lane >> 4;
  const int w    = t >> 6;
  const int wr   = w >> 1, wc = w & 1;
  const int m0 = blockIdx.y * 128;
  const int n0 = blockIdx.x * 128;
  const int srow = t >> 3;
  const int scol = (t & 7) * 8;

  f32x4 acc[4][4] = {};
  const __bf16* Ap = A  + (size_t)m0 * K;
  const __bf16* Bp = Bw + (size_t)n0 * K;

  for (int k0 = 0; k0 < K; k0 += 64) {
#pragma unroll
    for (int i = 0; i < 4; ++i) {
      const int row = i * 32 + srow;
      gll16(Ap + (size_t)row * K + k0 + scol, &As[row * 64 + scol]);
    }
#pragma unroll
    for (int i = 0; i < 4; ++i) {
      const int row = i * 32 + srow;
      gll16(Bp + (size_t)row * K + k0 + scol, &Bs[row * 64 + scol]);
    }
    __syncthreads();
#pragma unroll
    for (int ks = 0; ks < 2; ++ks) {
      bf16x8 af[4], bfr[4];
#pragma unroll
      for (int mi = 0; mi < 4; ++mi)
        af[mi] = *(const bf16x8*)&As[(wr * 64 + mi * 16 + l15) * 64 + ks * 32 + g * 8];
#pragma unroll
      for (int ni = 0; ni < 4; ++ni)
        bfr[ni] = *(const bf16x8*)&Bs[(wc * 64 + ni * 16 + l15) * 64 + ks * 32 + g * 8];
#pragma unroll
      for (int mi = 0; mi < 4; ++mi)
#pragma unroll
        for (int ni = 0; ni < 4; ++ni)
          acc[mi][ni] = __builtin_amdgcn_mfma_f32_16x16x32_bf16(af[mi], bfr[ni], acc[mi][ni], 0, 0, 0);
    }
    __syncthreads();
  }

  const int crow0 = m0 + wr * 64;
  const int ccol0 = n0 + wc * 64;
#pragma unroll
  for (int mi = 0; mi < 4; ++mi) {
#pragma unroll
    for (int r = 0; r < 4; ++r) {
      const int rr = crow0 + mi * 16 + 4 * g + r;
#pragma unroll
      for (int ni = 0; ni < 4; ++ni) {
        const int cc = ccol0 + ni * 16 + l15;
        float v = acc[mi][ni][r];
        if (BIAS) v += bias[cc];
        if (RES)  v += res[(size_t)rr * N + cc];
        Cout[(size_t)rr * N + cc] = v;
      }
    }
  }
}

// ---------------- causal flash attention (T2 swizzle + T14 async stage) -----
// grid (32 qtiles REVERSED, 16 h, 2 b), 256 thr / 4 waves, 16 q-rows/wave.
// K/V reg-staged 1 tile ahead (double reg set), LDS XOR-swizzled (row&7)<<4.
// Q pre-scaled by 0.125 in QKV epilogue; causal mask only on diagonal tile;
// defer-max skips rescale when no new max.
__global__ __launch_bounds__(256, 2)
void attn_kernel(const __bf16* __restrict__ qk, const __bf16* __restrict__ vT,
                 __bf16* __restrict__ ctx)
{
  __shared__ __bf16 Ks[64 * 64];       // [k][d] swizzled
  __shared__ __bf16 VTs[64 * 64];      // [d][k] swizzled
  __shared__ __bf16 Ps[4][16 * 64];    // per-wave P [q][k] swizzled
  const int t    = threadIdx.x;
  const int lane = t & 63;
  const int l15  = lane & 15;
  const int g    = lane >> 4;
  const int w    = t >> 6;
  const int qt = gridDim.x - 1 - blockIdx.x;   // heavy blocks dispatch first
  const int hh = blockIdx.y;
  const int bb = blockIdx.z;
  const int q0 = qt * 64;

  // Q fragments (already scaled by 1/8)
  const int qrow = q0 + w * 16 + l15;
  const size_t qkrow = ((size_t)(bb * 2048 + qrow)) * 2048 + hh * 64;
  bf16x8 qf0 = *(const bf16x8*)&qk[qkrow + g * 8];
  bf16x8 qf1 = *(const bf16x8*)&qk[qkrow + 32 + g * 8];

  // staging geometry: thread (kk=t>>2, c0=(t&3)*16), 2x16B each of K and V^T
  const int kk = t >> 2;
  const int c0 = (t & 3) * 16;
  const __bf16* kbase = &qk[((size_t)(bb * 2048) + kk) * 2048 + 1024 + hh * 64 + c0];
  const __bf16* vbase = &vT[(((size_t)(bb * 16 + hh)) * 64 + kk) * 2048 + c0];
  const int xw  = (kk & 7) << 4;
  char* kdst = (char*)Ks  + kk * 128;
  char* vdst = (char*)VTs + kk * 128;
  const int cw0 = ((((t & 3) * 2)    ) << 4) ^ xw;
  const int cw1 = ((((t & 3) * 2) + 1) << 4) ^ xw;

  f32x4 acc[4] = {};
  float mrun = -1e30f, lrun = 0.f;

  bf16x8 ka0, ka1, va0, va1, kb0, kb1, vb0, vb1;

  auto LOAD = [&](int kt, bf16x8& k0, bf16x8& k1, bf16x8& v0, bf16x8& v1) {
    const __bf16* kp = kbase + (size_t)kt * 64 * 2048;
    k0 = *(const bf16x8*)(kp);
    k1 = *(const bf16x8*)(kp + 8);
    const __bf16* vp = vbase + kt * 64;
    v0 = *(const bf16x8*)(vp);
    v1 = *(const bf16x8*)(vp + 8);
  };
  auto WRITE = [&](bf16x8& k0, bf16x8& k1, bf16x8& v0, bf16x8& v1) {
    *(bf16x8*)(kdst + cw0) = k0;
    *(bf16x8*)(kdst + cw1) = k1;
    *(bf16x8*)(vdst + cw0) = v0;
    *(bf16x8*)(vdst + cw1) = v1;
  };

  const int xr = (l15 & 7) << 4;
  char* pw = (char*)Ps[w] + l15 * 128;

  auto COMPUTE = [&](int kt) {
    // S^T = K @ Q^T : rows k (4 frags), cols q (16)
    f32x4 s[4];
#pragma unroll
    for (int f = 0; f < 4; ++f) {
      const char* kb = (const char*)Ks + (f * 16 + l15) * 128;
      bf16x8 a0 = *(const bf16x8*)(kb + ((g << 4) ^ xr));
      bf16x8 a1 = *(const bf16x8*)(kb + (((4 + g) << 4) ^ xr));
      f32x4 z = {};
      z = __builtin_amdgcn_mfma_f32_16x16x32_bf16(a0, qf0, z, 0, 0, 0);
      z = __builtin_amdgcn_mfma_f32_16x16x32_bf16(a1, qf1, z, 0, 0, 0);
      s[f] = z;
    }

    float pmax = -1e30f;
    if (kt == qt) {                       // only diagonal tile masks
      const int qg = q0 + w * 16 + l15;
#pragma unroll
      for (int f = 0; f < 4; ++f)
#pragma unroll
        for (int r = 0; r < 4; ++r) {
          const int kg = kt * 64 + f * 16 + g * 4 + r;
          if (kg > qg) s[f][r] = -1e30f;
          pmax = fmaxf(pmax, s[f][r]);
        }
    } else {
#pragma unroll
      for (int f = 0; f < 4; ++f)
#pragma unroll
        for (int r = 0; r < 4; ++r) pmax = fmaxf(pmax, s[f][r]);
    }
    pmax = fmaxf(pmax, __shfl_xor(pmax, 16));
    pmax = fmaxf(pmax, __shfl_xor(pmax, 32));

    if (__any(pmax > mrun)) {            // defer-max: skip rescale otherwise
      const float mnew  = fmaxf(mrun, pmax);
      const float alpha = __expf(mrun - mnew);
      float al[4];
#pragma unroll
      for (int r = 0; r < 4; ++r) al[r] = __shfl(alpha, g * 4 + r);
#pragma unroll
      for (int nf = 0; nf < 4; ++nf)
#pragma unroll
        for (int r = 0; r < 4; ++r) acc[nf][r] *= al[r];
      lrun *= alpha;
      mrun = mnew;
    }

    float lsum = 0.f;
#pragma unroll
    for (int f = 0; f < 4; ++f)
#pragma unroll
      for (int r = 0; r < 4; ++r) {
        float p = __expf(s[f][r] - mrun);
        s[f][r] = p;
        lsum += p;
      }
    lsum += __shfl_xor(lsum, 16);
    lsum += __shfl_xor(lsum, 32);
    lrun += lsum;

    // P -> LDS (bf16, swizzled, wave-private)
#pragma unroll
    for (int f = 0; f < 4; ++f) {
      bf16x4 pk;
      pk[0] = (__bf16)s[f][0]; pk[1] = (__bf16)s[f][1];
      pk[2] = (__bf16)s[f][2]; pk[3] = (__bf16)s[f][3];
      *(bf16x4*)(pw + ((((f * 2 + (g >> 1)) << 4) ^ xr) + (g & 1) * 8)) = pk;
    }
    asm volatile("s_waitcnt lgkmcnt(0)" ::: "memory");

    // ctx += P @ V
#pragma unroll
    for (int ks = 0; ks < 2; ++ks) {
      bf16x8 pa = *(const bf16x8*)(pw + (((ks * 4 + g) << 4) ^ xr));
#pragma unroll
      for (int nf = 0; nf < 4; ++nf) {
        const char* vb = (const char*)VTs + (nf * 16 + l15) * 128;
        bf16x8 vf = *(const bf16x8*)(vb + (((ks * 4 + g) << 4) ^ xr));
        acc[nf] = __builtin_amdgcn_mfma_f32_16x16x32_bf16(pa, vf, acc[nf], 0, 0, 0);
      }
    }
  };

  LOAD(0, ka0, ka1, va0, va1);
  int kt = 0;
  for (;;) {
    ASM_VMCNT0();
    __syncthreads();                      // all waves done reading prev tile
    WRITE(ka0, ka1, va0, va1);
    if (kt < qt) LOAD(kt + 1, kb0, kb1, vb0, vb1);   // in flight across compute
    __syncthreads();
    COMPUTE(kt);
    if (++kt > qt) break;

    ASM_VMCNT0();
    __syncthreads();
    WRITE(kb0, kb1, vb0, vb1);
    if (kt < qt) LOAD(kt + 1, ka0, ka1, va0, va1);
    __syncthreads();
    COMPUTE(kt);
    if (++kt > qt) break;
  }

  float li[4];
#pragma unroll
  for (int r = 0; r < 4; ++r) li[r] = 1.0f / __shfl(lrun, g * 4 + r);
#pragma unroll
  for (int nf = 0; nf < 4; ++nf)
#pragma unroll
    for (int r = 0; r < 4; ++r) {
      const int row = q0 + w * 16 + 4 * g + r;
      ctx[((size_t)(bb * 2048 + row)) * DD + hh * 64 + nf * 16 + l15] =
          (__bf16)(acc[nf][r] * li[r]);
    }
}

// ---------------- launcher ----------------
extern "C" void kernel_launch(void* const* d_in, const int* in_sizes, int n_in,
                              void* d_out, int out_size, void* d_ws, size_t ws_size,
                              hipStream_t stream)
{
  (void)in_sizes; (void)n_in; (void)out_size; (void)ws_size;
  const float* x  = (const float*)d_in[0];
  const float* wq = (const float*)d_in[1];
  const float* wk = (const float*)d_in[2];
  const float* wv = (const float*)d_in[3];
  const float* wo = (const float*)d_in[4];
  const float* bo = (const float*)d_in[5];
  const float* w1 = (const float*)d_in[6];
  const float* b1 = (const float*)d_in[7];
  const float* w2 = (const float*)d_in[8];
  const float* b2 = (const float*)d_in[9];
  const float* g1 = (const float*)d_in[10];
  const float* s1 = (const float*)d_in[11];
  const float* g2 = (const float*)d_in[12];
  const float* s2 = (const float*)d_in[13];
  float* out = (float*)d_out;

  char* ws = (char*)d_ws;
  __bf16* wbf  = (__bf16*)ws;                         // 24MB weights (q,k,v,o,w1,w2)
  __bf16* hbuf = (__bf16*)(ws + 25165824);            // 8MB
  __bf16* qkb  = (__bf16*)(ws + 33554432);            // 16MB, Q|K [4096][2048]
  __bf16* vbT  = (__bf16*)(ws + 50331648);            // 8MB,  V^T [2][16][64][2048]
  __bf16* ctxb = (__bf16*)(ws + 58720256);            // 8MB
  float*  x2   = (float*)(ws + 67108864);             // 16MB
  __bf16* ffb  = (__bf16*)(ws + 83886080);            // 32MB
  __bf16* part = (__bf16*)(ws + 33554432);            // 32MB, overlaps qkb..ctxb (dead post-WO)

  cvt_weights<<<12288, 256, 0, stream>>>(wq, wk, wv, wo, w1, w2, wbf);
  ln_kernel<<<1024, 256, 0, stream>>>(x, g1, s1, hbuf);

  // fused QKV: M=4096 N=3072 K=1024 (V transposed, Q pre-scaled in epilogue)
  gemm256<0><<<dim3(12, 16), 512, 0, stream>>>(
      hbuf, 1024, wbf, 1024, qkb, nullptr, vbT, NTOK, 3072, 1024);

  dim3 ga(32, 16, 2);
  attn_kernel<<<ga, 256, 0, stream>>>(qkb, vbT, ctxb);

  // WO: M=4096 N=1024 K=1024 (+bo, +x residual, f32)
  gemm_bt<true, true><<<dim3(8, 32), 256, 0, stream>>>(
      ctxb, wbf + 3145728, x2, bo, x, NTOK, DD, DD);
  ln_kernel<<<1024, 256, 0, stream>>>(x2, g2, s2, hbuf);

  // FF1: M=4096 N=4096 K=1024, bias+gelu -> bf16
  gemm256<1><<<dim3(16, 16), 512, 0, stream>>>(
      hbuf, 1024, wbf + 4194304, 1024, ffb, b1, nullptr, NTOK, FFD, 1024);

  // FF2 split-K (KS=4): bf16 partials, then fused reduce (+b2, +x2)
  gemm256<2><<<dim3(4, 16, 4), 512, 0, stream>>>(
      ffb, 4096, wbf + 8388608, 4096, part, nullptr, nullptr, NTOK, DD, 1024);
  ff2_reduce<<<4096, 256, 0, stream>>>(part, x2, b2, out);
}

// Round 8
// 237.073 us; speedup vs baseline: 1.5773x; 1.0201x over previous
//
#include <hip/hip_runtime.h>
#include <hip/hip_bf16.h>
#include <stdint.h>

// TransformerBlock: B=2 T=2048 D=1024 H=16 HD=64 FF=4096, causal, pre-LN.
// GEMMs + attention in bf16 MFMA (16x16x32), f32 accum, f32 residual path.

typedef __attribute__((ext_vector_type(8))) __bf16 bf16x8;
typedef __attribute__((ext_vector_type(4))) __bf16 bf16x4;
typedef __attribute__((ext_vector_type(4))) float  f32x4;

#define DD    1024
#define TSEQ  2048
#define NTOK  4096
#define FFD   4096

#define ASM_VMCNT0() asm volatile("s_waitcnt vmcnt(0)" ::: "memory")

__device__ __forceinline__ void gll16(const void* g, void* l) {
  __builtin_amdgcn_global_load_lds(
      (const __attribute__((address_space(1))) unsigned int*)g,
      (__attribute__((address_space(3))) unsigned int*)l, 16, 0, 0);
}

__device__ __forceinline__ float gelu_f(float v) {
  float u = 0.7978845608028654f * (v + 0.044715f * v * v * v);
  float t = 1.0f - 2.0f / (1.0f + __expf(2.0f * u));   // tanh(u)
  return 0.5f * v * (1.0f + t);
}

// ---------------- weight f32 -> bf16 convert ----------------
__global__ __launch_bounds__(256) void cvt_weights(
    const float* __restrict__ wq, const float* __restrict__ wk,
    const float* __restrict__ wv, const float* __restrict__ wo,
    const float* __restrict__ w1, const float* __restrict__ w2,
    __bf16* __restrict__ dst)
{
  size_t i4 = (size_t)blockIdx.x * 256 + threadIdx.x;
  size_t e = i4 * 4;
  const float* src; size_t off;
  if (e < (size_t)4 * 1048576) {
    int sel = (int)(e >> 20);
    src = sel == 0 ? wq : sel == 1 ? wk : sel == 2 ? wv : wo;
    off = e & 1048575;
  } else if (e < (size_t)8 * 1048576) {
    src = w1; off = e - (size_t)4 * 1048576;
  } else {
    src = w2; off = e - (size_t)8 * 1048576;
  }
  float4 v = *(const float4*)(src + off);
  bf16x4 o;
  o[0] = (__bf16)v.x; o[1] = (__bf16)v.y; o[2] = (__bf16)v.z; o[3] = (__bf16)v.w;
  *(bf16x4*)(dst + e) = o;
}

// ---------------- LayerNorm: one wave per row ----------------
__global__ __launch_bounds__(256) void ln_kernel(
    const float* __restrict__ x, const float* __restrict__ gw,
    const float* __restrict__ sw, __bf16* __restrict__ out)
{
  const int row  = blockIdx.x * 4 + (threadIdx.x >> 6);
  const int lane = threadIdx.x & 63;
  const float4* xr = (const float4*)(x + (size_t)row * DD);
  float4 v[4];
  float s = 0.f, sq = 0.f;
#pragma unroll
  for (int i = 0; i < 4; ++i) {
    v[i] = xr[i * 64 + lane];
    s  += v[i].x + v[i].y + v[i].z + v[i].w;
    sq += v[i].x * v[i].x + v[i].y * v[i].y + v[i].z * v[i].z + v[i].w * v[i].w;
  }
#pragma unroll
  for (int off = 32; off >= 1; off >>= 1) {
    s  += __shfl_xor(s, off);
    sq += __shfl_xor(sq, off);
  }
  const float mean = s * (1.f / DD);
  const float rstd = rsqrtf(sq * (1.f / DD) - mean * mean + 1e-5f);
  const float4* gr = (const float4*)gw;
  const float4* sr = (const float4*)sw;
#pragma unroll
  for (int i = 0; i < 4; ++i) {
    float4 gv = gr[i * 64 + lane];
    float4 sv = sr[i * 64 + lane];
    bf16x4 o;
    o[0] = (__bf16)(gv.x * (v[i].x - mean) * rstd + sv.x);
    o[1] = (__bf16)(gv.y * (v[i].y - mean) * rstd + sv.y);
    o[2] = (__bf16)(gv.z * (v[i].z - mean) * rstd + sv.z);
    o[3] = (__bf16)(gv.w * (v[i].w - mean) * rstd + sv.w);
    *(bf16x4*)&out[(size_t)row * DD + (size_t)(i * 64 + lane) * 4] = o;
  }
}

// ================= T3-minimum 2-phase 256x256 GEMM =================
// C[M,N] = A[M,K(lda)] @ Bw[N,K(ldb)]^T. 512 thr / 8 waves (2x4), BK=64.
// Per K-tile: STAGE(kt+1) issued FIRST (latency hidden by this tile's
// compute), 24 swizzled ds_read_b128 (precomputed base + imm offsets),
// 64 MFMA with COMPILER-managed lgkm interleave, one __syncthreads
// (vmcnt0+lgkm0+barrier = the 2-phase boundary, fence-safe).
// MODE: 0=QKV (bf16, V transposed to voutT, Q scaled 1/8), 1=bias+gelu bf16,
//       2=bf16 split-K partial.
template<int MODE>
__global__ __launch_bounds__(512, 2)
void gemm256(const __bf16* __restrict__ A, int lda,
             const __bf16* __restrict__ Bw, int ldb,
             __bf16* __restrict__ Cout, const float* __restrict__ bias,
             __bf16* __restrict__ voutT, int M, int N, int K)
{
  __shared__ __bf16 sm[65536];          // 2 bufs x (A 32KB | B 32KB)
  const int t = threadIdx.x;
  const int lane = t & 63;
  const int l15 = lane & 15, g = lane >> 4;
  const int w = t >> 6;
  const int wm = w >> 2, wn = w & 3;    // 2 x 4 wave grid
  const int m0 = blockIdx.y * 256, n0 = blockIdx.x * 256;

  if (MODE == 2) {                      // split-K offsets
    const int kz = blockIdx.z;
    A    += (size_t)kz * 1024;
    Bw   += (size_t)kz * 1024;
    Cout += (size_t)kz * (size_t)M * N;
  }

  // staging: thread covers rows {i*64+srow}, 16B chunk schunk, source chunk
  // XOR-swizzled (row&7 == srow&7 for all i -> gc is thread-constant).
  const int srow = t >> 3;
  const int schunk = t & 7;
  const int gc = schunk ^ (srow & 7);
  const __bf16* gA = A  + (size_t)(m0 + srow) * lda + gc * 8;
  const __bf16* gB = Bw + (size_t)(n0 + srow) * ldb + gc * 8;
  char* smb = (char*)sm;
  const int sdst = t * 16;              // + i*8192 per row-group

  auto STAGE = [&](int kt, int cur) {
    char* dA = smb + cur * 65536;
    char* dB = dA + 32768;
    const __bf16* a = gA + kt * 64;
    const __bf16* b = gB + kt * 64;
#pragma unroll
    for (int i = 0; i < 4; ++i)
      gll16(a + (size_t)i * 64 * lda, dA + i * 8192 + sdst);
#pragma unroll
    for (int i = 0; i < 4; ++i)
      gll16(b + (size_t)i * 64 * ldb, dB + i * 8192 + sdst);
  };

  // fragment read bases (bytes within buffer); frag row&7 == l15&7.
  const int xa = l15 & 7;
  const int baseA0 = (wm * 128 + l15) * 128 + ((g ^ xa) << 4);
  const int baseA1 = (wm * 128 + l15) * 128 + (((4 + g) ^ xa) << 4);
  const int baseB0 = 32768 + (wn * 64 + l15) * 128 + ((g ^ xa) << 4);
  const int baseB1 = 32768 + (wn * 64 + l15) * 128 + (((4 + g) ^ xa) << 4);

  f32x4 acc[8][4] = {};
  const int NT = K >> 6;

  STAGE(0, 0);
  __syncthreads();                      // tile 0 landed (vmcnt0 + barrier)

  for (int kt = 0; kt < NT; ++kt) {
    const int cur = kt & 1;
    if (kt + 1 < NT) STAGE(kt + 1, cur ^ 1);   // issue-early: full tile covers latency

    const char* bufb = smb + cur * 65536;
    bf16x8 af[8][2], bfr[4][2];
#pragma unroll
    for (int mi = 0; mi < 8; ++mi) {
      af[mi][0] = *(const bf16x8*)(bufb + baseA0 + mi * 2048);
      af[mi][1] = *(const bf16x8*)(bufb + baseA1 + mi * 2048);
    }
#pragma unroll
    for (int ni = 0; ni < 4; ++ni) {
      bfr[ni][0] = *(const bf16x8*)(bufb + baseB0 + ni * 2048);
      bfr[ni][1] = *(const bf16x8*)(bufb + baseB1 + ni * 2048);
    }
#pragma unroll
    for (int ks = 0; ks < 2; ++ks)
#pragma unroll
      for (int mi = 0; mi < 8; ++mi)
#pragma unroll
        for (int ni = 0; ni < 4; ++ni)
          acc[mi][ni] = __builtin_amdgcn_mfma_f32_16x16x32_bf16(
              af[mi][ks], bfr[ni][ks], acc[mi][ni], 0, 0, 0);

    __syncthreads();                    // drains stage (vmcnt0) + read-done
  }

  // epilogue: C/D frag layout col = lane&15, row = 4*(lane>>4)+r
#pragma unroll
  for (int mi = 0; mi < 8; ++mi) {
    const int rr0 = m0 + wm * 128 + mi * 16 + 4 * g;
#pragma unroll
    for (int ni = 0; ni < 4; ++ni) {
      const int cc = n0 + wn * 64 + ni * 16 + l15;
      if (MODE == 0 && n0 + wn * 64 >= 2048) {
        const int b  = rr0 >> 11;
        const int t0 = rr0 & 2047;
        const int vc = cc - 2048;
        const int h = vc >> 6, d = vc & 63;
        bf16x4 o;
        o[0] = (__bf16)acc[mi][ni][0]; o[1] = (__bf16)acc[mi][ni][1];
        o[2] = (__bf16)acc[mi][ni][2]; o[3] = (__bf16)acc[mi][ni][3];
        *(bf16x4*)&voutT[(((size_t)(b * 16 + h)) * 64 + d) * 2048 + t0] = o;
      } else {
        const int ldc = (MODE == 0) ? 2048 : N;
#pragma unroll
        for (int r = 0; r < 4; ++r) {
          float v = acc[mi][ni][r];
          if (MODE == 0 && cc < 1024) v *= 0.125f;   // fold 1/sqrt(HD) into Q
          if (MODE == 1) { v += bias[cc]; v = gelu_f(v); }
          Cout[(size_t)(rr0 + r) * ldc + cc] = (__bf16)v;
        }
      }
    }
  }
}

// ---------------- FF2 reduce: out = x2 + b2 + sum(partials) ----------------
// out has 4,194,304 elements; 256 thr x 4 elems -> EXACTLY 4096 blocks.
__global__ __launch_bounds__(256) void ff2_reduce(
    const __bf16* __restrict__ part, const float* __restrict__ x2,
    const float* __restrict__ b2, float* __restrict__ out)
{
  const size_t e = ((size_t)blockIdx.x * 256 + threadIdx.x) * 4;
  float4 r = *(const float4*)(x2 + e);
  const float4 b = *(const float4*)(b2 + (e & 1023));
  r.x += b.x; r.y += b.y; r.z += b.z; r.w += b.w;
#pragma unroll
  for (int s = 0; s < 4; ++s) {
    bf16x4 p = *(const bf16x4*)(part + (size_t)s * 4194304 + e);
    r.x += (float)p[0]; r.y += (float)p[1]; r.z += (float)p[2]; r.w += (float)p[3];
  }
  *(float4*)(out + e) = r;
}

// ---------------- legacy 128x128 GEMM (WO only) ----------------
template<bool BIAS, bool RES>
__global__ __launch_bounds__(256, 3)
void gemm_bt(const __bf16* __restrict__ A, const __bf16* __restrict__ Bw,
             float* __restrict__ Cout, const float* __restrict__ bias,
             const float* __restrict__ res, int M, int N, int K)
{
  __shared__ __bf16 As[128 * 64];
  __shared__ __bf16 Bs[128 * 64];
  const int t    = threadIdx.x;
  const int lane = t & 63;
  const int l15  = lane & 15;
  const int g    = lane >> 4;
  const int w    = t >> 6;
  const int wr   = w >> 1, wc = w & 1;
  const int m0 = blockIdx.y * 128;
  const int n0 = blockIdx.x * 128;
  const int srow = t >> 3;
  const int scol = (t & 7) * 8;

  f32x4 acc[4][4] = {};
  const __bf16* Ap = A  + (size_t)m0 * K;
  const __bf16* Bp = Bw + (size_t)n0 * K;

  for (int k0 = 0; k0 < K; k0 += 64) {
#pragma unroll
    for (int i = 0; i < 4; ++i) {
      const int row = i * 32 + srow;
      gll16(Ap + (size_t)row * K + k0 + scol, &As[row * 64 + scol]);
    }
#pragma unroll
    for (int i = 0; i < 4; ++i) {
      const int row = i * 32 + srow;
      gll16(Bp + (size_t)row * K + k0 + scol, &Bs[row * 64 + scol]);
    }
    __syncthreads();
#pragma unroll
    for (int ks = 0; ks < 2; ++ks) {
      bf16x8 af[4], bfr[4];
#pragma unroll
      for (int mi = 0; mi < 4; ++mi)
        af[mi] = *(const bf16x8*)&As[(wr * 64 + mi * 16 + l15) * 64 + ks * 32 + g * 8];
#pragma unroll
      for (int ni = 0; ni < 4; ++ni)
        bfr[ni] = *(const bf16x8*)&Bs[(wc * 64 + ni * 16 + l15) * 64 + ks * 32 + g * 8];
#pragma unroll
      for (int mi = 0; mi < 4; ++mi)
#pragma unroll
        for (int ni = 0; ni < 4; ++ni)
          acc[mi][ni] = __builtin_amdgcn_mfma_f32_16x16x32_bf16(af[mi], bfr[ni], acc[mi][ni], 0, 0, 0);
    }
    __syncthreads();
  }

  const int crow0 = m0 + wr * 64;
  const int ccol0 = n0 + wc * 64;
#pragma unroll
  for (int mi = 0; mi < 4; ++mi) {
#pragma unroll
    for (int r = 0; r < 4; ++r) {
      const int rr = crow0 + mi * 16 + 4 * g + r;
#pragma unroll
      for (int ni = 0; ni < 4; ++ni) {
        const int cc = ccol0 + ni * 16 + l15;
        float v = acc[mi][ni][r];
        if (BIAS) v += bias[cc];
        if (RES)  v += res[(size_t)rr * N + cc];
        Cout[(size_t)rr * N + cc] = v;
      }
    }
  }
}

// ---------------- causal flash attention (unchanged from R7) ----------------
__global__ __launch_bounds__(256, 2)
void attn_kernel(const __bf16* __restrict__ qk, const __bf16* __restrict__ vT,
                 __bf16* __restrict__ ctx)
{
  __shared__ __bf16 Ks[64 * 64];       // [k][d] swizzled
  __shared__ __bf16 VTs[64 * 64];      // [d][k] swizzled
  __shared__ __bf16 Ps[4][16 * 64];    // per-wave P [q][k] swizzled
  const int t    = threadIdx.x;
  const int lane = t & 63;
  const int l15  = lane & 15;
  const int g    = lane >> 4;
  const int w    = t >> 6;
  const int qt = gridDim.x - 1 - blockIdx.x;   // heavy blocks dispatch first
  const int hh = blockIdx.y;
  const int bb = blockIdx.z;
  const int q0 = qt * 64;

  const int qrow = q0 + w * 16 + l15;
  const size_t qkrow = ((size_t)(bb * 2048 + qrow)) * 2048 + hh * 64;
  bf16x8 qf0 = *(const bf16x8*)&qk[qkrow + g * 8];
  bf16x8 qf1 = *(const bf16x8*)&qk[qkrow + 32 + g * 8];

  const int kk = t >> 2;
  const int c0 = (t & 3) * 16;
  const __bf16* kbase = &qk[((size_t)(bb * 2048) + kk) * 2048 + 1024 + hh * 64 + c0];
  const __bf16* vbase = &vT[(((size_t)(bb * 16 + hh)) * 64 + kk) * 2048 + c0];
  const int xw  = (kk & 7) << 4;
  char* kdst = (char*)Ks  + kk * 128;
  char* vdst = (char*)VTs + kk * 128;
  const int cw0 = ((((t & 3) * 2)    ) << 4) ^ xw;
  const int cw1 = ((((t & 3) * 2) + 1) << 4) ^ xw;

  f32x4 acc[4] = {};
  float mrun = -1e30f, lrun = 0.f;

  bf16x8 ka0, ka1, va0, va1, kb0, kb1, vb0, vb1;

  auto LOAD = [&](int kt, bf16x8& k0, bf16x8& k1, bf16x8& v0, bf16x8& v1) {
    const __bf16* kp = kbase + (size_t)kt * 64 * 2048;
    k0 = *(const bf16x8*)(kp);
    k1 = *(const bf16x8*)(kp + 8);
    const __bf16* vp = vbase + kt * 64;
    v0 = *(const bf16x8*)(vp);
    v1 = *(const bf16x8*)(vp + 8);
  };
  auto WRITE = [&](bf16x8& k0, bf16x8& k1, bf16x8& v0, bf16x8& v1) {
    *(bf16x8*)(kdst + cw0) = k0;
    *(bf16x8*)(kdst + cw1) = k1;
    *(bf16x8*)(vdst + cw0) = v0;
    *(bf16x8*)(vdst + cw1) = v1;
  };

  const int xr = (l15 & 7) << 4;
  char* pw = (char*)Ps[w] + l15 * 128;

  auto COMPUTE = [&](int kt) {
    f32x4 s[4];
#pragma unroll
    for (int f = 0; f < 4; ++f) {
      const char* kb = (const char*)Ks + (f * 16 + l15) * 128;
      bf16x8 a0 = *(const bf16x8*)(kb + ((g << 4) ^ xr));
      bf16x8 a1 = *(const bf16x8*)(kb + (((4 + g) << 4) ^ xr));
      f32x4 z = {};
      z = __builtin_amdgcn_mfma_f32_16x16x32_bf16(a0, qf0, z, 0, 0, 0);
      z = __builtin_amdgcn_mfma_f32_16x16x32_bf16(a1, qf1, z, 0, 0, 0);
      s[f] = z;
    }

    float pmax = -1e30f;
    if (kt == qt) {
      const int qg = q0 + w * 16 + l15;
#pragma unroll
      for (int f = 0; f < 4; ++f)
#pragma unroll
        for (int r = 0; r < 4; ++r) {
          const int kg = kt * 64 + f * 16 + g * 4 + r;
          if (kg > qg) s[f][r] = -1e30f;
          pmax = fmaxf(pmax, s[f][r]);
        }
    } else {
#pragma unroll
      for (int f = 0; f < 4; ++f)
#pragma unroll
        for (int r = 0; r < 4; ++r) pmax = fmaxf(pmax, s[f][r]);
    }
    pmax = fmaxf(pmax, __shfl_xor(pmax, 16));
    pmax = fmaxf(pmax, __shfl_xor(pmax, 32));

    if (__any(pmax > mrun)) {
      const float mnew  = fmaxf(mrun, pmax);
      const float alpha = __expf(mrun - mnew);
      float al[4];
#pragma unroll
      for (int r = 0; r < 4; ++r) al[r] = __shfl(alpha, g * 4 + r);
#pragma unroll
      for (int nf = 0; nf < 4; ++nf)
#pragma unroll
        for (int r = 0; r < 4; ++r) acc[nf][r] *= al[r];
      lrun *= alpha;
      mrun = mnew;
    }

    float lsum = 0.f;
#pragma unroll
    for (int f = 0; f < 4; ++f)
#pragma unroll
      for (int r = 0; r < 4; ++r) {
        float p = __expf(s[f][r] - mrun);
        s[f][r] = p;
        lsum += p;
      }
    lsum += __shfl_xor(lsum, 16);
    lsum += __shfl_xor(lsum, 32);
    lrun += lsum;

#pragma unroll
    for (int f = 0; f < 4; ++f) {
      bf16x4 pk;
      pk[0] = (__bf16)s[f][0]; pk[1] = (__bf16)s[f][1];
      pk[2] = (__bf16)s[f][2]; pk[3] = (__bf16)s[f][3];
      *(bf16x4*)(pw + ((((f * 2 + (g >> 1)) << 4) ^ xr) + (g & 1) * 8)) = pk;
    }
    asm volatile("s_waitcnt lgkmcnt(0)" ::: "memory");

#pragma unroll
    for (int ks = 0; ks < 2; ++ks) {
      bf16x8 pa = *(const bf16x8*)(pw + (((ks * 4 + g) << 4) ^ xr));
#pragma unroll
      for (int nf = 0; nf < 4; ++nf) {
        const char* vb = (const char*)VTs + (nf * 16 + l15) * 128;
        bf16x8 vf = *(const bf16x8*)(vb + (((ks * 4 + g) << 4) ^ xr));
        acc[nf] = __builtin_amdgcn_mfma_f32_16x16x32_bf16(pa, vf, acc[nf], 0, 0, 0);
      }
    }
  };

  LOAD(0, ka0, ka1, va0, va1);
  int kt = 0;
  for (;;) {
    ASM_VMCNT0();
    __syncthreads();
    WRITE(ka0, ka1, va0, va1);
    if (kt < qt) LOAD(kt + 1, kb0, kb1, vb0, vb1);
    __syncthreads();
    COMPUTE(kt);
    if (++kt > qt) break;

    ASM_VMCNT0();
    __syncthreads();
    WRITE(kb0, kb1, vb0, vb1);
    if (kt < qt) LOAD(kt + 1, ka0, ka1, va0, va1);
    __syncthreads();
    COMPUTE(kt);
    if (++kt > qt) break;
  }

  float li[4];
#pragma unroll
  for (int r = 0; r < 4; ++r) li[r] = 1.0f / __shfl(lrun, g * 4 + r);
#pragma unroll
  for (int nf = 0; nf < 4; ++nf)
#pragma unroll
    for (int r = 0; r < 4; ++r) {
      const int row = q0 + w * 16 + 4 * g + r;
      ctx[((size_t)(bb * 2048 + row)) * DD + hh * 64 + nf * 16 + l15] =
          (__bf16)(acc[nf][r] * li[r]);
    }
}

// ---------------- launcher ----------------
extern "C" void kernel_launch(void* const* d_in, const int* in_sizes, int n_in,
                              void* d_out, int out_size, void* d_ws, size_t ws_size,
                              hipStream_t stream)
{
  (void)in_sizes; (void)n_in; (void)out_size; (void)ws_size;
  const float* x  = (const float*)d_in[0];
  const float* wq = (const float*)d_in[1];
  const float* wk = (const float*)d_in[2];
  const float* wv = (const float*)d_in[3];
  const float* wo = (const float*)d_in[4];
  const float* bo = (const float*)d_in[5];
  const float* w1 = (const float*)d_in[6];
  const float* b1 = (const float*)d_in[7];
  const float* w2 = (const float*)d_in[8];
  const float* b2 = (const float*)d_in[9];
  const float* g1 = (const float*)d_in[10];
  const float* s1 = (const float*)d_in[11];
  const float* g2 = (const float*)d_in[12];
  const float* s2 = (const float*)d_in[13];
  float* out = (float*)d_out;

  char* ws = (char*)d_ws;
  __bf16* wbf  = (__bf16*)ws;                         // 24MB weights (q,k,v,o,w1,w2)
  __bf16* hbuf = (__bf16*)(ws + 25165824);            // 8MB
  __bf16* qkb  = (__bf16*)(ws + 33554432);            // 16MB, Q|K [4096][2048]
  __bf16* vbT  = (__bf16*)(ws + 50331648);            // 8MB,  V^T [2][16][64][2048]
  __bf16* ctxb = (__bf16*)(ws + 58720256);            // 8MB
  float*  x2   = (float*)(ws + 67108864);             // 16MB
  __bf16* ffb  = (__bf16*)(ws + 83886080);            // 32MB
  __bf16* part = (__bf16*)(ws + 33554432);            // 32MB, overlaps qkb..ctxb (dead post-WO)

  cvt_weights<<<12288, 256, 0, stream>>>(wq, wk, wv, wo, w1, w2, wbf);
  ln_kernel<<<1024, 256, 0, stream>>>(x, g1, s1, hbuf);

  // fused QKV: M=4096 N=3072 K=1024 (V transposed, Q pre-scaled in epilogue)
  gemm256<0><<<dim3(12, 16), 512, 0, stream>>>(
      hbuf, 1024, wbf, 1024, qkb, nullptr, vbT, NTOK, 3072, 1024);

  dim3 ga(32, 16, 2);
  attn_kernel<<<ga, 256, 0, stream>>>(qkb, vbT, ctxb);

  // WO: M=4096 N=1024 K=1024 (+bo, +x residual, f32)
  gemm_bt<true, true><<<dim3(8, 32), 256, 0, stream>>>(
      ctxb, wbf + 3145728, x2, bo, x, NTOK, DD, DD);
  ln_kernel<<<1024, 256, 0, stream>>>(x2, g2, s2, hbuf);

  // FF1: M=4096 N=4096 K=1024, bias+gelu -> bf16
  gemm256<1><<<dim3(16, 16), 512, 0, stream>>>(
      hbuf, 1024, wbf + 4194304, 1024, ffb, b1, nullptr, NTOK, FFD, 1024);

  // FF2 split-K (KS=4): bf16 partials, then fused reduce (+b2, +x2)
  gemm256<2><<<dim3(4, 16, 4), 512, 0, stream>>>(
      ffb, 4096, wbf + 8388608, 4096, part, nullptr, nullptr, NTOK, DD, 1024);
  ff2_reduce<<<4096, 256, 0, stream>>>(part, x2, b2, out);
}